// Round 1
// baseline (14010.078 us; speedup 1.0000x reference)
//
#include <hip/hip_runtime.h>
#include <hip/hip_bf16.h>
#include <math.h>

// ---------------------------------------------------------------------------
// Model constants
// ---------------------------------------------------------------------------
#define NBATCH 5
#define SEQ    1024
#define T      1025          // SEQ + 1 (cls token)
#define ROWS   (NBATCH * T)  // 5125
#define DM     512
#define DFF    2048
#define NHEAD  8
#define HD     64
#define NTOK   51
#define MLPDIM 256
#define NCLS   7
#define GH     3
#define GHID   64
#define GCLS   5
#define NGRAPH (SEQ * 5)     // 5120

// ---------------------------------------------------------------------------
// Encoder: h[b,0,:] = cls_tok + pos_emb[0]; h[b,t+1,:] = x[b,t,:]@W_enc + b_enc + pos_emb[t+1]
// ---------------------------------------------------------------------------
__global__ __launch_bounds__(256) void encoder_kernel(
    const float* __restrict__ x, const float* __restrict__ W_enc,
    const float* __restrict__ b_enc, const float* __restrict__ cls_tok,
    const float* __restrict__ pos_emb, float* __restrict__ h)
{
    int row = blockIdx.x;              // 0..ROWS-1
    int b = row / T, tt = row % T;
    int tid = threadIdx.x;
    float* hp = h + (size_t)row * DM;
    if (tt == 0) {
        hp[tid]       = cls_tok[tid]       + pos_emb[tid];
        hp[tid + 256] = cls_tok[tid + 256] + pos_emb[tid + 256];
        return;
    }
    __shared__ float xs[NTOK];
    int s = tt - 1;
    if (tid < NTOK) xs[tid] = x[((size_t)b * SEQ + s) * NTOK + tid];
    __syncthreads();
    #pragma unroll
    for (int rep = 0; rep < 2; ++rep) {
        int d = tid + rep * 256;
        float acc = b_enc[d] + pos_emb[(size_t)tt * DM + d];
        for (int kx = 0; kx < NTOK; ++kx) acc += xs[kx] * W_enc[kx * DM + d];
        hp[d] = acc;
    }
}

// ---------------------------------------------------------------------------
// Generic fp32 tiled GEMM: C[M,N] = A[M,K] @ B[K,N] + bias, optional ReLU.
// 64x64 tile, BK=16, 256 threads, 4x4 per-thread micro-tile.
// N and K must be multiples of 64/16 (true for all call sites); M guarded.
// ---------------------------------------------------------------------------
#define BM 64
#define BN 64
#define BKK 16
__global__ __launch_bounds__(256) void gemm_kernel(
    const float* __restrict__ A, const float* __restrict__ B,
    const float* __restrict__ bias, float* __restrict__ C,
    int M, int N, int K, int relu)
{
    __shared__ float As[BKK][BM + 1];
    __shared__ float Bs[BKK][BN + 1];
    int bx = blockIdx.x;   // N tile
    int by = blockIdx.y;   // M tile
    int tid = threadIdx.x;
    int tx = tid & 15, ty = tid >> 4;
    int m0 = by * BM, n0 = bx * BN;
    float acc[4][4] = {};
    for (int k0 = 0; k0 < K; k0 += BKK) {
        #pragma unroll
        for (int i = 0; i < 4; ++i) {
            int e = tid + i * 256;
            int r = e >> 4, c = e & 15;
            int gm = m0 + r;
            As[c][r] = (gm < M) ? A[(size_t)gm * K + k0 + c] : 0.f;
        }
        #pragma unroll
        for (int i = 0; i < 4; ++i) {
            int e = tid + i * 256;
            int r = e >> 6, c = e & 63;
            Bs[r][c] = B[(size_t)(k0 + r) * N + n0 + c];
        }
        __syncthreads();
        #pragma unroll
        for (int kk = 0; kk < BKK; ++kk) {
            float av[4], bv[4];
            #pragma unroll
            for (int i = 0; i < 4; ++i) av[i] = As[kk][ty + 16 * i];
            #pragma unroll
            for (int j = 0; j < 4; ++j) bv[j] = Bs[kk][tx + 16 * j];
            #pragma unroll
            for (int i = 0; i < 4; ++i)
                #pragma unroll
                for (int j = 0; j < 4; ++j)
                    acc[i][j] += av[i] * bv[j];
        }
        __syncthreads();
    }
    #pragma unroll
    for (int i = 0; i < 4; ++i) {
        int gm = m0 + ty + 16 * i;
        if (gm >= M) continue;
        #pragma unroll
        for (int j = 0; j < 4; ++j) {
            int gn = n0 + tx + 16 * j;
            float val = acc[i][j] + bias[gn];
            if (relu) val = fmaxf(val, 0.f);
            C[(size_t)gm * N + gn] = val;
        }
    }
}

// ---------------------------------------------------------------------------
// Attention: one block per (query row t, b*8+h). Full-row softmax in LDS.
// q,k,v layout: (b, t, h, d) == row-major (ROWS, 512), col = h*64+d.
// ---------------------------------------------------------------------------
__global__ __launch_bounds__(256) void attn_kernel(
    const float* __restrict__ q, const float* __restrict__ k,
    const float* __restrict__ v, float* __restrict__ o)
{
    int t  = blockIdx.x;         // 0..T-1
    int bh = blockIdx.y;         // 0..39
    int b = bh >> 3, h = bh & 7;
    int tid = threadIdx.x;
    __shared__ float qs[HD];
    __shared__ float sc[T];
    __shared__ float red[256];
    __shared__ float part[4][HD];
    size_t base = (size_t)b * T * DM + h * HD;
    if (tid < HD) qs[tid] = q[base + (size_t)t * DM + tid];
    __syncthreads();
    for (int s = tid; s < T; s += 256) {
        const float* kp = k + base + (size_t)s * DM;
        float acc = 0.f;
        #pragma unroll
        for (int d4 = 0; d4 < HD / 4; ++d4) {
            float4 kv = reinterpret_cast<const float4*>(kp)[d4];
            acc += qs[d4*4+0]*kv.x + qs[d4*4+1]*kv.y + qs[d4*4+2]*kv.z + qs[d4*4+3]*kv.w;
        }
        sc[s] = acc * 0.125f;    // 1/sqrt(64)
    }
    __syncthreads();
    float m = -1e30f;
    for (int s = tid; s < T; s += 256) m = fmaxf(m, sc[s]);
    red[tid] = m; __syncthreads();
    for (int st = 128; st > 0; st >>= 1) {
        if (tid < st) red[tid] = fmaxf(red[tid], red[tid + st]);
        __syncthreads();
    }
    float mx = red[0];
    __syncthreads();
    float sum = 0.f;
    for (int s = tid; s < T; s += 256) { float e = expf(sc[s] - mx); sc[s] = e; sum += e; }
    red[tid] = sum; __syncthreads();
    for (int st = 128; st > 0; st >>= 1) {
        if (tid < st) red[tid] += red[tid + st];
        __syncthreads();
    }
    float inv = 1.f / red[0];
    int d = tid & 63, ch = tid >> 6;
    float acc = 0.f;
    for (int s = ch; s < T; s += 4) acc += sc[s] * v[base + (size_t)s * DM + d];
    part[ch][d] = acc; __syncthreads();
    if (tid < HD)
        o[base + (size_t)t * DM + tid] =
            (part[0][tid] + part[1][tid] + part[2][tid] + part[3][tid]) * inv;
}

// ---------------------------------------------------------------------------
// Fused residual + LayerNorm (in-place on h): h = LN(h + r)*g + be
// ---------------------------------------------------------------------------
__global__ __launch_bounds__(256) void add_ln_kernel(
    float* __restrict__ h, const float* __restrict__ r,
    const float* __restrict__ g, const float* __restrict__ be)
{
    int row = blockIdx.x;
    int tid = threadIdx.x;
    float* hp = h + (size_t)row * DM;
    const float* rp = r + (size_t)row * DM;
    __shared__ float red[256];
    float v0 = hp[tid] + rp[tid];
    float v1 = hp[tid + 256] + rp[tid + 256];
    red[tid] = v0 + v1; __syncthreads();
    for (int st = 128; st > 0; st >>= 1) {
        if (tid < st) red[tid] += red[tid + st];
        __syncthreads();
    }
    float mean = red[0] * (1.f / DM);
    __syncthreads();
    float d0 = v0 - mean, d1 = v1 - mean;
    red[tid] = d0 * d0 + d1 * d1; __syncthreads();
    for (int st = 128; st > 0; st >>= 1) {
        if (tid < st) red[tid] += red[tid + st];
        __syncthreads();
    }
    float inv = rsqrtf(red[0] * (1.f / DM) + 1e-5f);
    hp[tid]       = d0 * inv * g[tid]       + be[tid];
    hp[tid + 256] = d1 * inv * g[tid + 256] + be[tid + 256];
}

// ---------------------------------------------------------------------------
// Decoder head: out[b,:] = (h[b,0,:]@Wd1 + bd1)@Wd2 + bd2   (tiny; 1 block)
// ---------------------------------------------------------------------------
__global__ __launch_bounds__(256) void decoder_kernel(
    const float* __restrict__ h, const float* __restrict__ Wd1,
    const float* __restrict__ bd1, const float* __restrict__ Wd2,
    const float* __restrict__ bd2, float* __restrict__ out)
{
    __shared__ float t1s[MLPDIM];
    int tid = threadIdx.x;
    for (int b = 0; b < NBATCH; ++b) {
        const float* cls = h + (size_t)b * T * DM;   // row (b, 0)
        float acc = bd1[tid];
        for (int kx = 0; kx < DM; ++kx) acc += cls[kx] * Wd1[kx * MLPDIM + tid];
        t1s[tid] = acc;
        __syncthreads();
        if (tid < NCLS) {
            float a2 = bd2[tid];
            for (int kx = 0; kx < MLPDIM; ++kx) a2 += t1s[kx] * Wd2[kx * NCLS + tid];
            out[b * NCLS + tid] = a2;
        }
        __syncthreads();
    }
}

// ---------------------------------------------------------------------------
// GAT: one 64-thread block per tiny graph g = s*5 + j.
// xg[g][node n][c] = x[n, s, j*3 + c]   (node index == batch index!)
// ---------------------------------------------------------------------------
__global__ __launch_bounds__(64) void gat_kernel(
    const float* __restrict__ x, const int* __restrict__ adj,
    const float* __restrict__ Wg, const float* __restrict__ ag,
    const float* __restrict__ Wgo, const float* __restrict__ ago,
    float* __restrict__ out)
{
    int g = blockIdx.x;
    int s = g / 5, jj = g % 5;
    int tid = threadIdx.x;
    __shared__ float xs[5][3];
    __shared__ int adjs[25];
    __shared__ float hb[GH][5][GHID];
    __shared__ float o1[GH][5][GHID];
    __shared__ float srcb[GH][5], dstb[GH][5];
    __shared__ float attb[GH][5][5];
    __shared__ float h2[5][5], src2[5], dst2[5], att2[5][5], o2[5][5];

    if (tid < 15) { int n = tid / 3, c = tid % 3;
        xs[n][c] = x[(size_t)n * SEQ * NTOK + (size_t)s * NTOK + jj * 3 + c]; }
    if (tid < 25) adjs[tid] = adj[tid];
    __syncthreads();

    // layer-1 projections h = xg @ Wg[hh]  (3x64)
    #pragma unroll
    for (int hh = 0; hh < GH; ++hh)
        #pragma unroll
        for (int n = 0; n < 5; ++n)
            hb[hh][n][tid] = xs[n][0] * Wg[hh * 192 + tid]
                           + xs[n][1] * Wg[hh * 192 + 64 + tid]
                           + xs[n][2] * Wg[hh * 192 + 128 + tid];
    __syncthreads();

    if (tid < 15) { int hh = tid / 5, n = tid % 5; float a = 0.f;
        for (int f = 0; f < GHID; ++f) a += hb[hh][n][f] * ag[hh * 128 + f];
        srcb[hh][n] = a;
    } else if (tid >= 32 && tid < 47) { int t2 = tid - 32; int hh = t2 / 5, n = t2 % 5; float a = 0.f;
        for (int f = 0; f < GHID; ++f) a += hb[hh][n][f] * ag[hh * 128 + 64 + f];
        dstb[hh][n] = a;
    }
    __syncthreads();

    if (tid < 15) { int hh = tid / 5, i = tid % 5;
        float e[5]; float mx = -1e30f;
        #pragma unroll
        for (int j2 = 0; j2 < 5; ++j2) {
            float ev = srcb[hh][i] + dstb[hh][j2];
            ev = ev > 0.f ? ev : 0.2f * ev;          // leaky_relu(0.2)
            e[j2] = ev;
            if (adjs[i * 5 + j2] && ev > mx) mx = ev;
        }
        float sum = 0.f;
        #pragma unroll
        for (int j2 = 0; j2 < 5; ++j2) {
            float p = adjs[i * 5 + j2] ? expf(e[j2] - mx) : 0.f;
            e[j2] = p; sum += p;
        }
        float inv = 1.f / sum;
        #pragma unroll
        for (int j2 = 0; j2 < 5; ++j2) attb[hh][i][j2] = e[j2] * inv;
    }
    __syncthreads();

    // o1 = elu(att @ h)
    #pragma unroll
    for (int hh = 0; hh < GH; ++hh)
        #pragma unroll
        for (int n = 0; n < 5; ++n) {
            float a = 0.f;
            #pragma unroll
            for (int j2 = 0; j2 < 5; ++j2) a += attb[hh][n][j2] * hb[hh][j2][tid];
            o1[hh][n][tid] = a > 0.f ? a : expm1f(a);
        }
    __syncthreads();

    // layer-2: h2 = hcat @ Wgo  (hcat[n][hh*64+f] = o1[hh][n][f])
    if (tid < 25) { int n = tid / 5, m = tid % 5; float a = 0.f;
        for (int hh = 0; hh < GH; ++hh)
            for (int f = 0; f < GHID; ++f)
                a += o1[hh][n][f] * Wgo[(hh * GHID + f) * GCLS + m];
        h2[n][m] = a;
    }
    __syncthreads();

    if (tid < 5) { float a = 0.f;
        for (int m = 0; m < GCLS; ++m) a += h2[tid][m] * ago[m];
        src2[tid] = a;
    } else if (tid >= 8 && tid < 13) { int n = tid - 8; float a = 0.f;
        for (int m = 0; m < GCLS; ++m) a += h2[n][m] * ago[GCLS + m];
        dst2[n] = a;
    }
    __syncthreads();

    if (tid < 5) { int i = tid;
        float e[5]; float mx = -1e30f;
        #pragma unroll
        for (int j2 = 0; j2 < 5; ++j2) {
            float ev = src2[i] + dst2[j2];
            ev = ev > 0.f ? ev : 0.2f * ev;
            e[j2] = ev;
            if (adjs[i * 5 + j2] && ev > mx) mx = ev;
        }
        float sum = 0.f;
        #pragma unroll
        for (int j2 = 0; j2 < 5; ++j2) {
            float p = adjs[i * 5 + j2] ? expf(e[j2] - mx) : 0.f;
            e[j2] = p; sum += p;
        }
        float inv = 1.f / sum;
        #pragma unroll
        for (int j2 = 0; j2 < 5; ++j2) att2[i][j2] = e[j2] * inv;
    }
    __syncthreads();

    if (tid < 25) { int n = tid / 5, m = tid % 5; float a = 0.f;
        #pragma unroll
        for (int j2 = 0; j2 < 5; ++j2) a += att2[n][j2] * h2[j2][m];
        o2[n][m] = a > 0.f ? a : expm1f(a);
    }
    __syncthreads();

    if (tid < 5) { int n = tid;
        float mx = o2[n][0];
        #pragma unroll
        for (int m = 1; m < GCLS; ++m) mx = fmaxf(mx, o2[n][m]);
        float sum = 0.f;
        #pragma unroll
        for (int m = 0; m < GCLS; ++m) sum += expf(o2[n][m] - mx);
        float ls = logf(sum);
        #pragma unroll
        for (int m = 0; m < GCLS; ++m)
            out[(size_t)g * 25 + n * 5 + m] = o2[n][m] - mx - ls;
    }
}

// ---------------------------------------------------------------------------
// Launch
// ---------------------------------------------------------------------------
extern "C" void kernel_launch(void* const* d_in, const int* in_sizes, int n_in,
                              void* d_out, int out_size, void* d_ws, size_t ws_size,
                              hipStream_t stream)
{
    const float* x       = (const float*)d_in[0];
    const int*   adj     = (const int*)  d_in[1];
    const float* W_enc   = (const float*)d_in[2];
    const float* b_enc   = (const float*)d_in[3];
    const float* cls_tok = (const float*)d_in[4];
    const float* pos_emb = (const float*)d_in[5];
    const float* Wq = (const float*)d_in[6];
    const float* bq = (const float*)d_in[7];
    const float* Wk = (const float*)d_in[8];
    const float* bk = (const float*)d_in[9];
    const float* Wv = (const float*)d_in[10];
    const float* bv = (const float*)d_in[11];
    const float* Wo = (const float*)d_in[12];
    const float* bo = (const float*)d_in[13];
    const float* W1 = (const float*)d_in[14];
    const float* b1 = (const float*)d_in[15];
    const float* W2 = (const float*)d_in[16];
    const float* b2 = (const float*)d_in[17];
    const float* g1 = (const float*)d_in[18];
    const float* be1= (const float*)d_in[19];
    const float* g2 = (const float*)d_in[20];
    const float* be2= (const float*)d_in[21];
    const float* Wd1= (const float*)d_in[22];
    const float* bd1= (const float*)d_in[23];
    const float* Wd2= (const float*)d_in[24];
    const float* bd2= (const float*)d_in[25];
    const float* Wg = (const float*)d_in[26];
    const float* ag = (const float*)d_in[27];
    const float* Wgo= (const float*)d_in[28];
    const float* ago= (const float*)d_in[29];
    float* out = (float*)d_out;

    // workspace layout (floats): h | q | k | v | o_pre | f1   ≈ 90.1 MiB
    float* ws   = (float*)d_ws;
    float* h    = ws;
    float* q    = h    + (size_t)ROWS * DM;
    float* kbuf = q    + (size_t)ROWS * DM;
    float* v    = kbuf + (size_t)ROWS * DM;
    float* opre = v    + (size_t)ROWS * DM;
    float* f1   = opre + (size_t)ROWS * DM;

    // Independent GAT branch (writes d_out[35..])
    gat_kernel<<<NGRAPH, 64, 0, stream>>>(x, adj, Wg, ag, Wgo, ago, out + NBATCH * NCLS);

    // Encoder
    encoder_kernel<<<ROWS, 256, 0, stream>>>(x, W_enc, b_enc, cls_tok, pos_emb, h);

    dim3 gN512(DM  / BN, (ROWS + BM - 1) / BM);   // (8, 81)
    dim3 gN2048(DFF / BN, (ROWS + BM - 1) / BM);  // (32, 81)

    for (int i = 0; i < 4; ++i) {
        gemm_kernel<<<gN512, 256, 0, stream>>>(h, Wq + (size_t)i*DM*DM, bq + i*DM, q,    ROWS, DM, DM, 0);
        gemm_kernel<<<gN512, 256, 0, stream>>>(h, Wk + (size_t)i*DM*DM, bk + i*DM, kbuf, ROWS, DM, DM, 0);
        gemm_kernel<<<gN512, 256, 0, stream>>>(h, Wv + (size_t)i*DM*DM, bv + i*DM, v,    ROWS, DM, DM, 0);
        attn_kernel<<<dim3(T, NBATCH * NHEAD), 256, 0, stream>>>(q, kbuf, v, opre);
        gemm_kernel<<<gN512, 256, 0, stream>>>(opre, Wo + (size_t)i*DM*DM, bo + i*DM, q, ROWS, DM, DM, 0);
        add_ln_kernel<<<ROWS, 256, 0, stream>>>(h, q, g1 + i*DM, be1 + i*DM);
        gemm_kernel<<<gN2048, 256, 0, stream>>>(h,  W1 + (size_t)i*DM*DFF, b1 + i*DFF, f1,   ROWS, DFF, DM, 1);
        gemm_kernel<<<gN512, 256, 0, stream>>>(f1, W2 + (size_t)i*DFF*DM, b2 + i*DM,  kbuf, ROWS, DM, DFF, 0);
        add_ln_kernel<<<ROWS, 256, 0, stream>>>(h, kbuf, g2 + i*DM, be2 + i*DM);
    }

    decoder_kernel<<<1, 256, 0, stream>>>(h, Wd1, bd1, Wd2, bd2, out);
}

// Round 2
// 4649.795 us; speedup vs baseline: 3.0131x; 3.0131x over previous
//
#include <hip/hip_runtime.h>
#include <hip/hip_bf16.h>
#include <math.h>

// ---------------------------------------------------------------------------
// Model constants
// ---------------------------------------------------------------------------
#define NBATCH 5
#define SEQ    1024
#define T      1025          // SEQ + 1 (cls token)
#define ROWS   (NBATCH * T)  // 5125
#define DM     512
#define DFF    2048
#define NHEAD  8
#define HD     64
#define NTOK   51
#define MLPDIM 256
#define NCLS   7
#define GH     3
#define GHID   64
#define GCLS   5
#define NGRAPH (SEQ * 5)     // 5120

// ---------------------------------------------------------------------------
// Encoder: h[b,0,:] = cls_tok + pos_emb[0]; h[b,t+1,:] = x[b,t,:]@W_enc + b_enc + pos_emb[t+1]
// ---------------------------------------------------------------------------
__global__ __launch_bounds__(256) void encoder_kernel(
    const float* __restrict__ x, const float* __restrict__ W_enc,
    const float* __restrict__ b_enc, const float* __restrict__ cls_tok,
    const float* __restrict__ pos_emb, float* __restrict__ h)
{
    int row = blockIdx.x;              // 0..ROWS-1
    int b = row / T, tt = row % T;
    int tid = threadIdx.x;
    float* hp = h + (size_t)row * DM;
    if (tt == 0) {
        hp[tid]       = cls_tok[tid]       + pos_emb[tid];
        hp[tid + 256] = cls_tok[tid + 256] + pos_emb[tid + 256];
        return;
    }
    __shared__ float xs[NTOK];
    int s = tt - 1;
    if (tid < NTOK) xs[tid] = x[((size_t)b * SEQ + s) * NTOK + tid];
    __syncthreads();
    #pragma unroll
    for (int rep = 0; rep < 2; ++rep) {
        int d = tid + rep * 256;
        float acc = b_enc[d] + pos_emb[(size_t)tt * DM + d];
        for (int kx = 0; kx < NTOK; ++kx) acc += xs[kx] * W_enc[kx * DM + d];
        hp[d] = acc;
    }
}

// ---------------------------------------------------------------------------
// Generic fp32 tiled GEMM: C[M,N] = A[M,K] @ B[K,N] + bias, optional ReLU.
// 64x64 tile, BK=16, 256 threads, 4x4 per-thread micro-tile.
// ---------------------------------------------------------------------------
#define BM 64
#define BN 64
#define BKK 16
__global__ __launch_bounds__(256) void gemm_kernel(
    const float* __restrict__ A, const float* __restrict__ B,
    const float* __restrict__ bias, float* __restrict__ C,
    int M, int N, int K, int relu)
{
    __shared__ float As[BKK][BM + 1];
    __shared__ float Bs[BKK][BN + 1];
    int bx = blockIdx.x;   // N tile
    int by = blockIdx.y;   // M tile
    int tid = threadIdx.x;
    int tx = tid & 15, ty = tid >> 4;
    int m0 = by * BM, n0 = bx * BN;
    float acc[4][4] = {};
    for (int k0 = 0; k0 < K; k0 += BKK) {
        #pragma unroll
        for (int i = 0; i < 4; ++i) {
            int e = tid + i * 256;
            int r = e >> 4, c = e & 15;
            int gm = m0 + r;
            As[c][r] = (gm < M) ? A[(size_t)gm * K + k0 + c] : 0.f;
        }
        #pragma unroll
        for (int i = 0; i < 4; ++i) {
            int e = tid + i * 256;
            int r = e >> 6, c = e & 63;
            Bs[r][c] = B[(size_t)(k0 + r) * N + n0 + c];
        }
        __syncthreads();
        #pragma unroll
        for (int kk = 0; kk < BKK; ++kk) {
            float av[4], bv[4];
            #pragma unroll
            for (int i = 0; i < 4; ++i) av[i] = As[kk][ty + 16 * i];
            #pragma unroll
            for (int j = 0; j < 4; ++j) bv[j] = Bs[kk][tx + 16 * j];
            #pragma unroll
            for (int i = 0; i < 4; ++i)
                #pragma unroll
                for (int j = 0; j < 4; ++j)
                    acc[i][j] += av[i] * bv[j];
        }
        __syncthreads();
    }
    #pragma unroll
    for (int i = 0; i < 4; ++i) {
        int gm = m0 + ty + 16 * i;
        if (gm >= M) continue;
        #pragma unroll
        for (int j = 0; j < 4; ++j) {
            int gn = n0 + tx + 16 * j;
            float val = acc[i][j] + bias[gn];
            if (relu) val = fmaxf(val, 0.f);
            C[(size_t)gm * N + gn] = val;
        }
    }
}

// ---------------------------------------------------------------------------
// Flash-style attention: one block per (bh, 64-query tile).
// Per 64-key chunk: S = Q K^T (register 4x4 micro-tile GEMM from LDS),
// online softmax (shfl row-reductions), P via LDS, O += P V.
// Layouts: Qs/KVs(K phase) transposed [d][row]; Ps [s][i]; KVs(V phase) [s][d].
// Leading dim 68 keeps float4 rows 16B-aligned (68*4=272 % 16 == 0).
// ---------------------------------------------------------------------------
#define AQ 64
#define AC 64
__global__ __launch_bounds__(256) void attn_kernel(
    const float* __restrict__ q, const float* __restrict__ k,
    const float* __restrict__ v, float* __restrict__ o)
{
    __shared__ float Qs[64][68];   // [d][i], pre-scaled by 1/8
    __shared__ float KVs[64][68];  // K phase: [d][j]; V phase: [s][d]
    __shared__ float Ps[64][68];   // [s][i]
    int bh = blockIdx.y;           // 0..39
    int b = bh >> 3, h = bh & 7;
    int t0 = blockIdx.x * AQ;
    int tid = threadIdx.x;
    int tx = tid & 15, ty = tid >> 4;
    size_t base = (size_t)b * T * DM + h * HD;

    // Load Q tile transposed, scale folded in
    #pragma unroll
    for (int i = 0; i < 4; ++i) {
        int e = tid + i * 256;
        int r = e >> 4, c4 = (e & 15) * 4;
        int gr = t0 + r; if (gr >= T) gr = T - 1;
        float4 qv = *reinterpret_cast<const float4*>(q + base + (size_t)gr * DM + c4);
        Qs[c4 + 0][r] = qv.x * 0.125f;
        Qs[c4 + 1][r] = qv.y * 0.125f;
        Qs[c4 + 2][r] = qv.z * 0.125f;
        Qs[c4 + 3][r] = qv.w * 0.125f;
    }

    float oacc[4][4] = {};
    float mrow[4] = {-1e30f, -1e30f, -1e30f, -1e30f};
    float lrow[4] = {};

    for (int c0 = 0; c0 < T; c0 += AC) {
        __syncthreads();   // prev PV reads done before overwriting KVs
        #pragma unroll
        for (int i = 0; i < 4; ++i) {
            int e = tid + i * 256;
            int r = e >> 4, c4 = (e & 15) * 4;
            int gs = c0 + r; if (gs >= T) gs = T - 1;
            float4 kv = *reinterpret_cast<const float4*>(k + base + (size_t)gs * DM + c4);
            KVs[c4 + 0][r] = kv.x; KVs[c4 + 1][r] = kv.y;
            KVs[c4 + 2][r] = kv.z; KVs[c4 + 3][r] = kv.w;
        }
        __syncthreads();

        // S = Q K^T  (rows i = ty*4+ii, cols j = tx*4+jj)
        float s[4][4] = {};
        for (int kk = 0; kk < 64; ++kk) {
            float4 a4 = *reinterpret_cast<const float4*>(&Qs[kk][ty * 4]);
            float4 b4 = *reinterpret_cast<const float4*>(&KVs[kk][tx * 4]);
            float av[4] = {a4.x, a4.y, a4.z, a4.w};
            float bv[4] = {b4.x, b4.y, b4.z, b4.w};
            #pragma unroll
            for (int ii = 0; ii < 4; ++ii)
                #pragma unroll
                for (int jj = 0; jj < 4; ++jj)
                    s[ii][jj] += av[ii] * bv[jj];
        }
        // mask invalid keys
        #pragma unroll
        for (int jj = 0; jj < 4; ++jj) {
            int gs = c0 + tx * 4 + jj;
            if (gs >= T) {
                #pragma unroll
                for (int ii = 0; ii < 4; ++ii) s[ii][jj] = -1e30f;
            }
        }
        // online softmax
        #pragma unroll
        for (int ii = 0; ii < 4; ++ii) {
            float cm = fmaxf(fmaxf(s[ii][0], s[ii][1]), fmaxf(s[ii][2], s[ii][3]));
            #pragma unroll
            for (int off = 1; off < 16; off <<= 1)
                cm = fmaxf(cm, __shfl_xor(cm, off));
            float mnew = fmaxf(mrow[ii], cm);
            float alpha = __expf(mrow[ii] - mnew);
            mrow[ii] = mnew;
            float rs = 0.f;
            #pragma unroll
            for (int jj = 0; jj < 4; ++jj) {
                float p = __expf(s[ii][jj] - mnew);
                s[ii][jj] = p; rs += p;
            }
            #pragma unroll
            for (int off = 1; off < 16; off <<= 1)
                rs += __shfl_xor(rs, off);
            lrow[ii] = lrow[ii] * alpha + rs;
            #pragma unroll
            for (int jj = 0; jj < 4; ++jj) oacc[ii][jj] *= alpha;
        }
        __syncthreads();   // S-phase reads of KVs done
        // write P transposed [s][i]; load V natural [s][d]
        #pragma unroll
        for (int ii = 0; ii < 4; ++ii)
            #pragma unroll
            for (int jj = 0; jj < 4; ++jj)
                Ps[tx * 4 + jj][ty * 4 + ii] = s[ii][jj];
        #pragma unroll
        for (int i = 0; i < 4; ++i) {
            int e = tid + i * 256;
            int r = e >> 4, c4 = (e & 15) * 4;
            int gs = c0 + r; if (gs >= T) gs = T - 1;
            float4 vv = *reinterpret_cast<const float4*>(v + base + (size_t)gs * DM + c4);
            *reinterpret_cast<float4*>(&KVs[r][c4]) = vv;
        }
        __syncthreads();
        // O += P V
        for (int ss = 0; ss < 64; ++ss) {
            float4 a4 = *reinterpret_cast<const float4*>(&Ps[ss][ty * 4]);
            float4 b4 = *reinterpret_cast<const float4*>(&KVs[ss][tx * 4]);
            float av[4] = {a4.x, a4.y, a4.z, a4.w};
            float bv[4] = {b4.x, b4.y, b4.z, b4.w};
            #pragma unroll
            for (int ii = 0; ii < 4; ++ii)
                #pragma unroll
                for (int jj = 0; jj < 4; ++jj)
                    oacc[ii][jj] += av[ii] * bv[jj];
        }
    }

    #pragma unroll
    for (int ii = 0; ii < 4; ++ii) {
        int gr = t0 + ty * 4 + ii;
        if (gr >= T) continue;
        float inv = 1.f / lrow[ii];
        float4 ov;
        ov.x = oacc[ii][0] * inv; ov.y = oacc[ii][1] * inv;
        ov.z = oacc[ii][2] * inv; ov.w = oacc[ii][3] * inv;
        *reinterpret_cast<float4*>(o + base + (size_t)gr * DM + tx * 4) = ov;
    }
}

// ---------------------------------------------------------------------------
// Fused residual + LayerNorm (in-place on h): h = LN(h + r)*g + be
// ---------------------------------------------------------------------------
__global__ __launch_bounds__(256) void add_ln_kernel(
    float* __restrict__ h, const float* __restrict__ r,
    const float* __restrict__ g, const float* __restrict__ be)
{
    int row = blockIdx.x;
    int tid = threadIdx.x;
    float* hp = h + (size_t)row * DM;
    const float* rp = r + (size_t)row * DM;
    __shared__ float red[256];
    float v0 = hp[tid] + rp[tid];
    float v1 = hp[tid + 256] + rp[tid + 256];
    red[tid] = v0 + v1; __syncthreads();
    for (int st = 128; st > 0; st >>= 1) {
        if (tid < st) red[tid] += red[tid + st];
        __syncthreads();
    }
    float mean = red[0] * (1.f / DM);
    __syncthreads();
    float d0 = v0 - mean, d1 = v1 - mean;
    red[tid] = d0 * d0 + d1 * d1; __syncthreads();
    for (int st = 128; st > 0; st >>= 1) {
        if (tid < st) red[tid] += red[tid + st];
        __syncthreads();
    }
    float inv = rsqrtf(red[0] * (1.f / DM) + 1e-5f);
    hp[tid]       = d0 * inv * g[tid]       + be[tid];
    hp[tid + 256] = d1 * inv * g[tid + 256] + be[tid + 256];
}

// ---------------------------------------------------------------------------
// Decoder head: out[b,:] = (h[b,0,:]@Wd1 + bd1)@Wd2 + bd2   (tiny; 1 block)
// ---------------------------------------------------------------------------
__global__ __launch_bounds__(256) void decoder_kernel(
    const float* __restrict__ h, const float* __restrict__ Wd1,
    const float* __restrict__ bd1, const float* __restrict__ Wd2,
    const float* __restrict__ bd2, float* __restrict__ out)
{
    __shared__ float t1s[MLPDIM];
    int tid = threadIdx.x;
    for (int b = 0; b < NBATCH; ++b) {
        const float* cls = h + (size_t)b * T * DM;   // row (b, 0)
        float acc = bd1[tid];
        for (int kx = 0; kx < DM; ++kx) acc += cls[kx] * Wd1[kx * MLPDIM + tid];
        t1s[tid] = acc;
        __syncthreads();
        if (tid < NCLS) {
            float a2 = bd2[tid];
            for (int kx = 0; kx < MLPDIM; ++kx) a2 += t1s[kx] * Wd2[kx * NCLS + tid];
            out[b * NCLS + tid] = a2;
        }
        __syncthreads();
    }
}

// ---------------------------------------------------------------------------
// GAT: one 64-thread block per tiny graph g = s*5 + j.
// xg[g][node n][c] = x[n, s, j*3 + c]   (node index == batch index!)
// ---------------------------------------------------------------------------
__global__ __launch_bounds__(64) void gat_kernel(
    const float* __restrict__ x, const int* __restrict__ adj,
    const float* __restrict__ Wg, const float* __restrict__ ag,
    const float* __restrict__ Wgo, const float* __restrict__ ago,
    float* __restrict__ out)
{
    int g = blockIdx.x;
    int s = g / 5, jj = g % 5;
    int tid = threadIdx.x;
    __shared__ float xs[5][3];
    __shared__ int adjs[25];
    __shared__ float hb[GH][5][GHID];
    __shared__ float o1[GH][5][GHID];
    __shared__ float srcb[GH][5], dstb[GH][5];
    __shared__ float attb[GH][5][5];
    __shared__ float h2[5][5], src2[5], dst2[5], att2[5][5], o2[5][5];

    if (tid < 15) { int n = tid / 3, c = tid % 3;
        xs[n][c] = x[(size_t)n * SEQ * NTOK + (size_t)s * NTOK + jj * 3 + c]; }
    if (tid < 25) adjs[tid] = adj[tid];
    __syncthreads();

    #pragma unroll
    for (int hh = 0; hh < GH; ++hh)
        #pragma unroll
        for (int n = 0; n < 5; ++n)
            hb[hh][n][tid] = xs[n][0] * Wg[hh * 192 + tid]
                           + xs[n][1] * Wg[hh * 192 + 64 + tid]
                           + xs[n][2] * Wg[hh * 192 + 128 + tid];
    __syncthreads();

    if (tid < 15) { int hh = tid / 5, n = tid % 5; float a = 0.f;
        for (int f = 0; f < GHID; ++f) a += hb[hh][n][f] * ag[hh * 128 + f];
        srcb[hh][n] = a;
    } else if (tid >= 32 && tid < 47) { int t2 = tid - 32; int hh = t2 / 5, n = t2 % 5; float a = 0.f;
        for (int f = 0; f < GHID; ++f) a += hb[hh][n][f] * ag[hh * 128 + 64 + f];
        dstb[hh][n] = a;
    }
    __syncthreads();

    if (tid < 15) { int hh = tid / 5, i = tid % 5;
        float e[5]; float mx = -1e30f;
        #pragma unroll
        for (int j2 = 0; j2 < 5; ++j2) {
            float ev = srcb[hh][i] + dstb[hh][j2];
            ev = ev > 0.f ? ev : 0.2f * ev;
            e[j2] = ev;
            if (adjs[i * 5 + j2] && ev > mx) mx = ev;
        }
        float sum = 0.f;
        #pragma unroll
        for (int j2 = 0; j2 < 5; ++j2) {
            float p = adjs[i * 5 + j2] ? expf(e[j2] - mx) : 0.f;
            e[j2] = p; sum += p;
        }
        float inv = 1.f / sum;
        #pragma unroll
        for (int j2 = 0; j2 < 5; ++j2) attb[hh][i][j2] = e[j2] * inv;
    }
    __syncthreads();

    #pragma unroll
    for (int hh = 0; hh < GH; ++hh)
        #pragma unroll
        for (int n = 0; n < 5; ++n) {
            float a = 0.f;
            #pragma unroll
            for (int j2 = 0; j2 < 5; ++j2) a += attb[hh][n][j2] * hb[hh][j2][tid];
            o1[hh][n][tid] = a > 0.f ? a : expm1f(a);
        }
    __syncthreads();

    if (tid < 25) { int n = tid / 5, m = tid % 5; float a = 0.f;
        for (int hh = 0; hh < GH; ++hh)
            for (int f = 0; f < GHID; ++f)
                a += o1[hh][n][f] * Wgo[(hh * GHID + f) * GCLS + m];
        h2[n][m] = a;
    }
    __syncthreads();

    if (tid < 5) { float a = 0.f;
        for (int m = 0; m < GCLS; ++m) a += h2[tid][m] * ago[m];
        src2[tid] = a;
    } else if (tid >= 8 && tid < 13) { int n = tid - 8; float a = 0.f;
        for (int m = 0; m < GCLS; ++m) a += h2[n][m] * ago[GCLS + m];
        dst2[n] = a;
    }
    __syncthreads();

    if (tid < 5) { int i = tid;
        float e[5]; float mx = -1e30f;
        #pragma unroll
        for (int j2 = 0; j2 < 5; ++j2) {
            float ev = src2[i] + dst2[j2];
            ev = ev > 0.f ? ev : 0.2f * ev;
            e[j2] = ev;
            if (adjs[i * 5 + j2] && ev > mx) mx = ev;
        }
        float sum = 0.f;
        #pragma unroll
        for (int j2 = 0; j2 < 5; ++j2) {
            float p = adjs[i * 5 + j2] ? expf(e[j2] - mx) : 0.f;
            e[j2] = p; sum += p;
        }
        float inv = 1.f / sum;
        #pragma unroll
        for (int j2 = 0; j2 < 5; ++j2) att2[i][j2] = e[j2] * inv;
    }
    __syncthreads();

    if (tid < 25) { int n = tid / 5, m = tid % 5; float a = 0.f;
        #pragma unroll
        for (int j2 = 0; j2 < 5; ++j2) a += att2[n][j2] * h2[j2][m];
        o2[n][m] = a > 0.f ? a : expm1f(a);
    }
    __syncthreads();

    if (tid < 5) { int n = tid;
        float mx = o2[n][0];
        #pragma unroll
        for (int m = 1; m < GCLS; ++m) mx = fmaxf(mx, o2[n][m]);
        float sum = 0.f;
        #pragma unroll
        for (int m = 0; m < GCLS; ++m) sum += expf(o2[n][m] - mx);
        float ls = logf(sum);
        #pragma unroll
        for (int m = 0; m < GCLS; ++m)
            out[(size_t)g * 25 + n * 5 + m] = o2[n][m] - mx - ls;
    }
}

// ---------------------------------------------------------------------------
// Launch
// ---------------------------------------------------------------------------
extern "C" void kernel_launch(void* const* d_in, const int* in_sizes, int n_in,
                              void* d_out, int out_size, void* d_ws, size_t ws_size,
                              hipStream_t stream)
{
    const float* x       = (const float*)d_in[0];
    const int*   adj     = (const int*)  d_in[1];
    const float* W_enc   = (const float*)d_in[2];
    const float* b_enc   = (const float*)d_in[3];
    const float* cls_tok = (const float*)d_in[4];
    const float* pos_emb = (const float*)d_in[5];
    const float* Wq = (const float*)d_in[6];
    const float* bq = (const float*)d_in[7];
    const float* Wk = (const float*)d_in[8];
    const float* bk = (const float*)d_in[9];
    const float* Wv = (const float*)d_in[10];
    const float* bv = (const float*)d_in[11];
    const float* Wo = (const float*)d_in[12];
    const float* bo = (const float*)d_in[13];
    const float* W1 = (const float*)d_in[14];
    const float* b1 = (const float*)d_in[15];
    const float* W2 = (const float*)d_in[16];
    const float* b2 = (const float*)d_in[17];
    const float* g1 = (const float*)d_in[18];
    const float* be1= (const float*)d_in[19];
    const float* g2 = (const float*)d_in[20];
    const float* be2= (const float*)d_in[21];
    const float* Wd1= (const float*)d_in[22];
    const float* bd1= (const float*)d_in[23];
    const float* Wd2= (const float*)d_in[24];
    const float* bd2= (const float*)d_in[25];
    const float* Wg = (const float*)d_in[26];
    const float* ag = (const float*)d_in[27];
    const float* Wgo= (const float*)d_in[28];
    const float* ago= (const float*)d_in[29];
    float* out = (float*)d_out;

    float* ws   = (float*)d_ws;
    float* h    = ws;
    float* q    = h    + (size_t)ROWS * DM;
    float* kbuf = q    + (size_t)ROWS * DM;
    float* v    = kbuf + (size_t)ROWS * DM;
    float* opre = v    + (size_t)ROWS * DM;
    float* f1   = opre + (size_t)ROWS * DM;

    gat_kernel<<<NGRAPH, 64, 0, stream>>>(x, adj, Wg, ag, Wgo, ago, out + NBATCH * NCLS);
    encoder_kernel<<<ROWS, 256, 0, stream>>>(x, W_enc, b_enc, cls_tok, pos_emb, h);

    dim3 gN512(DM  / BN, (ROWS + BM - 1) / BM);   // (8, 81)
    dim3 gN2048(DFF / BN, (ROWS + BM - 1) / BM);  // (32, 81)
    dim3 gAttn((T + AQ - 1) / AQ, NBATCH * NHEAD); // (17, 40)

    for (int i = 0; i < 4; ++i) {
        gemm_kernel<<<gN512, 256, 0, stream>>>(h, Wq + (size_t)i*DM*DM, bq + i*DM, q,    ROWS, DM, DM, 0);
        gemm_kernel<<<gN512, 256, 0, stream>>>(h, Wk + (size_t)i*DM*DM, bk + i*DM, kbuf, ROWS, DM, DM, 0);
        gemm_kernel<<<gN512, 256, 0, stream>>>(h, Wv + (size_t)i*DM*DM, bv + i*DM, v,    ROWS, DM, DM, 0);
        attn_kernel<<<gAttn, 256, 0, stream>>>(q, kbuf, v, opre);
        gemm_kernel<<<gN512, 256, 0, stream>>>(opre, Wo + (size_t)i*DM*DM, bo + i*DM, q, ROWS, DM, DM, 0);
        add_ln_kernel<<<ROWS, 256, 0, stream>>>(h, q, g1 + i*DM, be1 + i*DM);
        gemm_kernel<<<gN2048, 256, 0, stream>>>(h,  W1 + (size_t)i*DM*DFF, b1 + i*DFF, f1,   ROWS, DFF, DM, 1);
        gemm_kernel<<<gN512, 256, 0, stream>>>(f1, W2 + (size_t)i*DFF*DM, b2 + i*DM,  kbuf, ROWS, DM, DFF, 0);
        add_ln_kernel<<<ROWS, 256, 0, stream>>>(h, kbuf, g2 + i*DM, be2 + i*DM);
    }

    decoder_kernel<<<1, 256, 0, stream>>>(h, Wd1, bd1, Wd2, bd2, out);
}

// Round 3
// 1715.969 us; speedup vs baseline: 8.1645x; 2.7097x over previous
//
#include <hip/hip_runtime.h>
#include <hip/hip_bf16.h>
#include <math.h>

// ---------------------------------------------------------------------------
// Model constants
// ---------------------------------------------------------------------------
#define NBATCH 5
#define SEQ    1024
#define T      1025          // SEQ + 1 (cls token)
#define ROWS   (NBATCH * T)  // 5125
#define MP     5248          // ROWS padded to 41*128 for MFMA tiles
#define DM     512
#define DFF    2048
#define NHEAD  8
#define HD     64
#define NTOK   51
#define MLPDIM 256
#define NCLS   7
#define GH     3
#define GHID   64
#define GCLS   5
#define NGRAPH (SEQ * 5)     // 5120

typedef __attribute__((ext_vector_type(8))) short bf16x8;
typedef __attribute__((ext_vector_type(4))) float f32x4;

#define GM_AS(p)  ((const __attribute__((address_space(1))) void*)(p))
#define LDS_AS(p) ((__attribute__((address_space(3))) void*)(p))

__device__ __forceinline__ unsigned short f2bf(float f) {
    unsigned int u = __float_as_uint(f);
    unsigned int r = (u + 0x7FFFu + ((u >> 16) & 1u)) >> 16;
    return (unsigned short)r;
}

// ---------------------------------------------------------------------------
// Weight transpose + fp32->bf16: W[K][N] (per mat) -> Wt[N][K]. blockIdx.z = mat.
// ---------------------------------------------------------------------------
__global__ __launch_bounds__(256) void wconv_kernel(
    const float* __restrict__ W, unsigned short* __restrict__ Wt, int K, int N)
{
    const float* Wm = W + (size_t)blockIdx.z * K * N;
    unsigned short* Wo = Wt + (size_t)blockIdx.z * K * N;
    __shared__ float tile[32][33];
    int bx = blockIdx.x * 32;   // N dir
    int by = blockIdx.y * 32;   // K dir
    int tx = threadIdx.x & 31, ty = threadIdx.x >> 5;   // 32 x 8
    #pragma unroll
    for (int i = 0; i < 32; i += 8)
        tile[ty + i][tx] = Wm[(size_t)(by + ty + i) * N + bx + tx];
    __syncthreads();
    #pragma unroll
    for (int i = 0; i < 32; i += 8)
        Wo[(size_t)(bx + ty + i) * K + by + tx] = f2bf(tile[tx][ty + i]);
}

// ---------------------------------------------------------------------------
// bf16 MFMA GEMM (m97 structure): C[M][N] = A[M][K] @ Bt[N][K]^T + bias.
// 128x128 block tile, BK=32, 256 threads = 4 waves in 2x2, each wave 64x64
// (4x4 tiles of v_mfma_f32_16x16x32_bf16). global_load_lds width=16 staging.
// M == gridDim.y*128 (padded); pad rows produce garbage that is never read.
// Out: fp32 (Cf) or bf16 (Cb), optional relu.
// ---------------------------------------------------------------------------
__global__ __launch_bounds__(256) void gemm_mfma(
    const unsigned short* __restrict__ A, const unsigned short* __restrict__ Bt,
    const float* __restrict__ bias, float* __restrict__ Cf,
    unsigned short* __restrict__ Cb, int N, int K, int relu)
{
    __shared__ unsigned short As[128 * 32];
    __shared__ unsigned short Bs[128 * 32];
    int tid = threadIdx.x;
    int l = tid & 63, w = tid >> 6;
    int wr = w & 1, wc = w >> 1;
    int mlane = l & 15, quad = l >> 4;
    int m0 = blockIdx.y * 128, n0 = blockIdx.x * 128;

    f32x4 acc[4][4] = {};   // [mi][ni]

    for (int k0 = 0; k0 < K; k0 += 32) {
        __syncthreads();
        #pragma unroll
        for (int it = 0; it < 2; ++it) {
            int c = tid + it * 256;          // 16B chunk id, 4 chunks/row
            int row = c >> 2, cc = c & 3;
            const unsigned short* ga = A  + (size_t)(m0 + row) * K + k0 + cc * 8;
            __builtin_amdgcn_global_load_lds(GM_AS(ga), LDS_AS(As + c * 8), 16, 0, 0);
            const unsigned short* gb = Bt + (size_t)(n0 + row) * K + k0 + cc * 8;
            __builtin_amdgcn_global_load_lds(GM_AS(gb), LDS_AS(Bs + c * 8), 16, 0, 0);
        }
        __syncthreads();
        bf16x8 afrag[4], bfrag[4];
        #pragma unroll
        for (int mi = 0; mi < 4; ++mi)
            afrag[mi] = *(const bf16x8*)(As + (wr * 64 + mi * 16 + mlane) * 32 + quad * 8);
        #pragma unroll
        for (int ni = 0; ni < 4; ++ni)
            bfrag[ni] = *(const bf16x8*)(Bs + (wc * 64 + ni * 16 + mlane) * 32 + quad * 8);
        #pragma unroll
        for (int mi = 0; mi < 4; ++mi)
            #pragma unroll
            for (int ni = 0; ni < 4; ++ni)
                acc[mi][ni] = __builtin_amdgcn_mfma_f32_16x16x32_bf16(
                    afrag[mi], bfrag[ni], acc[mi][ni], 0, 0, 0);
    }

    // C/D layout: col = lane&15, row = quad*4 + reg
    #pragma unroll
    for (int mi = 0; mi < 4; ++mi) {
        #pragma unroll
        for (int r = 0; r < 4; ++r) {
            int gm = m0 + wr * 64 + mi * 16 + quad * 4 + r;
            size_t rowoff = (size_t)gm * N;
            #pragma unroll
            for (int ni = 0; ni < 4; ++ni) {
                int gn = n0 + wc * 64 + ni * 16 + mlane;
                float val = acc[mi][ni][r] + bias[gn];
                if (relu) val = fmaxf(val, 0.f);
                if (Cb) Cb[rowoff + gn] = f2bf(val);
                else    Cf[rowoff + gn] = val;
            }
        }
    }
}

// ---------------------------------------------------------------------------
// Encoder: writes fp32 h and bf16 shadow hb
// ---------------------------------------------------------------------------
__global__ __launch_bounds__(256) void encoder_kernel(
    const float* __restrict__ x, const float* __restrict__ W_enc,
    const float* __restrict__ b_enc, const float* __restrict__ cls_tok,
    const float* __restrict__ pos_emb, float* __restrict__ h,
    unsigned short* __restrict__ hb)
{
    int row = blockIdx.x;
    int b = row / T, tt = row % T;
    int tid = threadIdx.x;
    float* hp = h + (size_t)row * DM;
    unsigned short* hbp = hb + (size_t)row * DM;
    if (tt == 0) {
        float a0 = cls_tok[tid]       + pos_emb[tid];
        float a1 = cls_tok[tid + 256] + pos_emb[tid + 256];
        hp[tid] = a0; hp[tid + 256] = a1;
        hbp[tid] = f2bf(a0); hbp[tid + 256] = f2bf(a1);
        return;
    }
    __shared__ float xs[NTOK];
    int s = tt - 1;
    if (tid < NTOK) xs[tid] = x[((size_t)b * SEQ + s) * NTOK + tid];
    __syncthreads();
    #pragma unroll
    for (int rep = 0; rep < 2; ++rep) {
        int d = tid + rep * 256;
        float acc = b_enc[d] + pos_emb[(size_t)tt * DM + d];
        for (int kx = 0; kx < NTOK; ++kx) acc += xs[kx] * W_enc[kx * DM + d];
        hp[d] = acc;
        hbp[d] = f2bf(acc);
    }
}

// ---------------------------------------------------------------------------
// Flash-style attention (fp32), writes bf16 output directly.
// ---------------------------------------------------------------------------
#define AQ 64
#define AC 64
__global__ __launch_bounds__(256) void attn_kernel(
    const float* __restrict__ q, const float* __restrict__ k,
    const float* __restrict__ v, unsigned short* __restrict__ ob)
{
    __shared__ float Qs[64][68];
    __shared__ float KVs[64][68];
    __shared__ float Ps[64][68];
    int bh = blockIdx.y;
    int b = bh >> 3, h = bh & 7;
    int t0 = blockIdx.x * AQ;
    int tid = threadIdx.x;
    int tx = tid & 15, ty = tid >> 4;
    size_t base = (size_t)b * T * DM + h * HD;

    #pragma unroll
    for (int i = 0; i < 4; ++i) {
        int e = tid + i * 256;
        int r = e >> 4, c4 = (e & 15) * 4;
        int gr = t0 + r; if (gr >= T) gr = T - 1;
        float4 qv = *reinterpret_cast<const float4*>(q + base + (size_t)gr * DM + c4);
        Qs[c4 + 0][r] = qv.x * 0.125f;
        Qs[c4 + 1][r] = qv.y * 0.125f;
        Qs[c4 + 2][r] = qv.z * 0.125f;
        Qs[c4 + 3][r] = qv.w * 0.125f;
    }

    float oacc[4][4] = {};
    float mrow[4] = {-1e30f, -1e30f, -1e30f, -1e30f};
    float lrow[4] = {};

    for (int c0 = 0; c0 < T; c0 += AC) {
        __syncthreads();
        #pragma unroll
        for (int i = 0; i < 4; ++i) {
            int e = tid + i * 256;
            int r = e >> 4, c4 = (e & 15) * 4;
            int gs = c0 + r; if (gs >= T) gs = T - 1;
            float4 kv = *reinterpret_cast<const float4*>(k + base + (size_t)gs * DM + c4);
            KVs[c4 + 0][r] = kv.x; KVs[c4 + 1][r] = kv.y;
            KVs[c4 + 2][r] = kv.z; KVs[c4 + 3][r] = kv.w;
        }
        __syncthreads();

        float s[4][4] = {};
        for (int kk = 0; kk < 64; ++kk) {
            float4 a4 = *reinterpret_cast<const float4*>(&Qs[kk][ty * 4]);
            float4 b4 = *reinterpret_cast<const float4*>(&KVs[kk][tx * 4]);
            float av[4] = {a4.x, a4.y, a4.z, a4.w};
            float bv[4] = {b4.x, b4.y, b4.z, b4.w};
            #pragma unroll
            for (int ii = 0; ii < 4; ++ii)
                #pragma unroll
                for (int jj = 0; jj < 4; ++jj)
                    s[ii][jj] += av[ii] * bv[jj];
        }
        #pragma unroll
        for (int jj = 0; jj < 4; ++jj) {
            int gs = c0 + tx * 4 + jj;
            if (gs >= T) {
                #pragma unroll
                for (int ii = 0; ii < 4; ++ii) s[ii][jj] = -1e30f;
            }
        }
        #pragma unroll
        for (int ii = 0; ii < 4; ++ii) {
            float cm = fmaxf(fmaxf(s[ii][0], s[ii][1]), fmaxf(s[ii][2], s[ii][3]));
            #pragma unroll
            for (int off = 1; off < 16; off <<= 1)
                cm = fmaxf(cm, __shfl_xor(cm, off));
            float mnew = fmaxf(mrow[ii], cm);
            float alpha = __expf(mrow[ii] - mnew);
            mrow[ii] = mnew;
            float rs = 0.f;
            #pragma unroll
            for (int jj = 0; jj < 4; ++jj) {
                float p = __expf(s[ii][jj] - mnew);
                s[ii][jj] = p; rs += p;
            }
            #pragma unroll
            for (int off = 1; off < 16; off <<= 1)
                rs += __shfl_xor(rs, off);
            lrow[ii] = lrow[ii] * alpha + rs;
            #pragma unroll
            for (int jj = 0; jj < 4; ++jj) oacc[ii][jj] *= alpha;
        }
        __syncthreads();
        #pragma unroll
        for (int ii = 0; ii < 4; ++ii)
            #pragma unroll
            for (int jj = 0; jj < 4; ++jj)
                Ps[tx * 4 + jj][ty * 4 + ii] = s[ii][jj];
        #pragma unroll
        for (int i = 0; i < 4; ++i) {
            int e = tid + i * 256;
            int r = e >> 4, c4 = (e & 15) * 4;
            int gs = c0 + r; if (gs >= T) gs = T - 1;
            float4 vv = *reinterpret_cast<const float4*>(v + base + (size_t)gs * DM + c4);
            *reinterpret_cast<float4*>(&KVs[r][c4]) = vv;
        }
        __syncthreads();
        for (int ss = 0; ss < 64; ++ss) {
            float4 a4 = *reinterpret_cast<const float4*>(&Ps[ss][ty * 4]);
            float4 b4 = *reinterpret_cast<const float4*>(&KVs[ss][tx * 4]);
            float av[4] = {a4.x, a4.y, a4.z, a4.w};
            float bv[4] = {b4.x, b4.y, b4.z, b4.w};
            #pragma unroll
            for (int ii = 0; ii < 4; ++ii)
                #pragma unroll
                for (int jj = 0; jj < 4; ++jj)
                    oacc[ii][jj] += av[ii] * bv[jj];
        }
    }

    #pragma unroll
    for (int ii = 0; ii < 4; ++ii) {
        int gr = t0 + ty * 4 + ii;
        if (gr >= T) continue;
        float inv = 1.f / lrow[ii];
        ushort4 pk;
        pk.x = f2bf(oacc[ii][0] * inv); pk.y = f2bf(oacc[ii][1] * inv);
        pk.z = f2bf(oacc[ii][2] * inv); pk.w = f2bf(oacc[ii][3] * inv);
        *reinterpret_cast<ushort4*>(ob + base + (size_t)gr * DM + tx * 4) = pk;
    }
}

// ---------------------------------------------------------------------------
// Fused residual + LayerNorm: h = LN(h + r)*g + be; writes bf16 shadow hb
// ---------------------------------------------------------------------------
__global__ __launch_bounds__(256) void add_ln_kernel(
    float* __restrict__ h, const float* __restrict__ r,
    const float* __restrict__ g, const float* __restrict__ be,
    unsigned short* __restrict__ hb)
{
    int row = blockIdx.x;
    int tid = threadIdx.x;
    float* hp = h + (size_t)row * DM;
    unsigned short* hbp = hb + (size_t)row * DM;
    const float* rp = r + (size_t)row * DM;
    __shared__ float red[256];
    float v0 = hp[tid] + rp[tid];
    float v1 = hp[tid + 256] + rp[tid + 256];
    red[tid] = v0 + v1; __syncthreads();
    for (int st = 128; st > 0; st >>= 1) {
        if (tid < st) red[tid] += red[tid + st];
        __syncthreads();
    }
    float mean = red[0] * (1.f / DM);
    __syncthreads();
    float d0 = v0 - mean, d1 = v1 - mean;
    red[tid] = d0 * d0 + d1 * d1; __syncthreads();
    for (int st = 128; st > 0; st >>= 1) {
        if (tid < st) red[tid] += red[tid + st];
        __syncthreads();
    }
    float inv = rsqrtf(red[0] * (1.f / DM) + 1e-5f);
    float o0 = d0 * inv * g[tid]       + be[tid];
    float o1 = d1 * inv * g[tid + 256] + be[tid + 256];
    hp[tid] = o0; hp[tid + 256] = o1;
    hbp[tid] = f2bf(o0); hbp[tid + 256] = f2bf(o1);
}

// ---------------------------------------------------------------------------
// Decoder head
// ---------------------------------------------------------------------------
__global__ __launch_bounds__(256) void decoder_kernel(
    const float* __restrict__ h, const float* __restrict__ Wd1,
    const float* __restrict__ bd1, const float* __restrict__ Wd2,
    const float* __restrict__ bd2, float* __restrict__ out)
{
    __shared__ float t1s[MLPDIM];
    int tid = threadIdx.x;
    for (int b = 0; b < NBATCH; ++b) {
        const float* cls = h + (size_t)b * T * DM;
        float acc = bd1[tid];
        for (int kx = 0; kx < DM; ++kx) acc += cls[kx] * Wd1[kx * MLPDIM + tid];
        t1s[tid] = acc;
        __syncthreads();
        if (tid < NCLS) {
            float a2 = bd2[tid];
            for (int kx = 0; kx < MLPDIM; ++kx) a2 += t1s[kx] * Wd2[kx * NCLS + tid];
            out[b * NCLS + tid] = a2;
        }
        __syncthreads();
    }
}

// ---------------------------------------------------------------------------
// GAT (unchanged)
// ---------------------------------------------------------------------------
__global__ __launch_bounds__(64) void gat_kernel(
    const float* __restrict__ x, const int* __restrict__ adj,
    const float* __restrict__ Wg, const float* __restrict__ ag,
    const float* __restrict__ Wgo, const float* __restrict__ ago,
    float* __restrict__ out)
{
    int g = blockIdx.x;
    int s = g / 5, jj = g % 5;
    int tid = threadIdx.x;
    __shared__ float xs[5][3];
    __shared__ int adjs[25];
    __shared__ float hb[GH][5][GHID];
    __shared__ float o1[GH][5][GHID];
    __shared__ float srcb[GH][5], dstb[GH][5];
    __shared__ float attb[GH][5][5];
    __shared__ float h2[5][5], src2[5], dst2[5], att2[5][5], o2[5][5];

    if (tid < 15) { int n = tid / 3, c = tid % 3;
        xs[n][c] = x[(size_t)n * SEQ * NTOK + (size_t)s * NTOK + jj * 3 + c]; }
    if (tid < 25) adjs[tid] = adj[tid];
    __syncthreads();

    #pragma unroll
    for (int hh = 0; hh < GH; ++hh)
        #pragma unroll
        for (int n = 0; n < 5; ++n)
            hb[hh][n][tid] = xs[n][0] * Wg[hh * 192 + tid]
                           + xs[n][1] * Wg[hh * 192 + 64 + tid]
                           + xs[n][2] * Wg[hh * 192 + 128 + tid];
    __syncthreads();

    if (tid < 15) { int hh = tid / 5, n = tid % 5; float a = 0.f;
        for (int f = 0; f < GHID; ++f) a += hb[hh][n][f] * ag[hh * 128 + f];
        srcb[hh][n] = a;
    } else if (tid >= 32 && tid < 47) { int t2 = tid - 32; int hh = t2 / 5, n = t2 % 5; float a = 0.f;
        for (int f = 0; f < GHID; ++f) a += hb[hh][n][f] * ag[hh * 128 + 64 + f];
        dstb[hh][n] = a;
    }
    __syncthreads();

    if (tid < 15) { int hh = tid / 5, i = tid % 5;
        float e[5]; float mx = -1e30f;
        #pragma unroll
        for (int j2 = 0; j2 < 5; ++j2) {
            float ev = srcb[hh][i] + dstb[hh][j2];
            ev = ev > 0.f ? ev : 0.2f * ev;
            e[j2] = ev;
            if (adjs[i * 5 + j2] && ev > mx) mx = ev;
        }
        float sum = 0.f;
        #pragma unroll
        for (int j2 = 0; j2 < 5; ++j2) {
            float p = adjs[i * 5 + j2] ? expf(e[j2] - mx) : 0.f;
            e[j2] = p; sum += p;
        }
        float inv = 1.f / sum;
        #pragma unroll
        for (int j2 = 0; j2 < 5; ++j2) attb[hh][i][j2] = e[j2] * inv;
    }
    __syncthreads();

    #pragma unroll
    for (int hh = 0; hh < GH; ++hh)
        #pragma unroll
        for (int n = 0; n < 5; ++n) {
            float a = 0.f;
            #pragma unroll
            for (int j2 = 0; j2 < 5; ++j2) a += attb[hh][n][j2] * hb[hh][j2][tid];
            o1[hh][n][tid] = a > 0.f ? a : expm1f(a);
        }
    __syncthreads();

    if (tid < 25) { int n = tid / 5, m = tid % 5; float a = 0.f;
        for (int hh = 0; hh < GH; ++hh)
            for (int f = 0; f < GHID; ++f)
                a += o1[hh][n][f] * Wgo[(hh * GHID + f) * GCLS + m];
        h2[n][m] = a;
    }
    __syncthreads();

    if (tid < 5) { float a = 0.f;
        for (int m = 0; m < GCLS; ++m) a += h2[tid][m] * ago[m];
        src2[tid] = a;
    } else if (tid >= 8 && tid < 13) { int n = tid - 8; float a = 0.f;
        for (int m = 0; m < GCLS; ++m) a += h2[n][m] * ago[GCLS + m];
        dst2[n] = a;
    }
    __syncthreads();

    if (tid < 5) { int i = tid;
        float e[5]; float mx = -1e30f;
        #pragma unroll
        for (int j2 = 0; j2 < 5; ++j2) {
            float ev = src2[i] + dst2[j2];
            ev = ev > 0.f ? ev : 0.2f * ev;
            e[j2] = ev;
            if (adjs[i * 5 + j2] && ev > mx) mx = ev;
        }
        float sum = 0.f;
        #pragma unroll
        for (int j2 = 0; j2 < 5; ++j2) {
            float p = adjs[i * 5 + j2] ? expf(e[j2] - mx) : 0.f;
            e[j2] = p; sum += p;
        }
        float inv = 1.f / sum;
        #pragma unroll
        for (int j2 = 0; j2 < 5; ++j2) att2[i][j2] = e[j2] * inv;
    }
    __syncthreads();

    if (tid < 25) { int n = tid / 5, m = tid % 5; float a = 0.f;
        #pragma unroll
        for (int j2 = 0; j2 < 5; ++j2) a += att2[n][j2] * h2[j2][m];
        o2[n][m] = a > 0.f ? a : expm1f(a);
    }
    __syncthreads();

    if (tid < 5) { int n = tid;
        float mx = o2[n][0];
        #pragma unroll
        for (int m = 1; m < GCLS; ++m) mx = fmaxf(mx, o2[n][m]);
        float sum = 0.f;
        #pragma unroll
        for (int m = 0; m < GCLS; ++m) sum += expf(o2[n][m] - mx);
        float ls = logf(sum);
        #pragma unroll
        for (int m = 0; m < GCLS; ++m)
            out[(size_t)g * 25 + n * 5 + m] = o2[n][m] - mx - ls;
    }
}

// ---------------------------------------------------------------------------
// Launch
// ---------------------------------------------------------------------------
extern "C" void kernel_launch(void* const* d_in, const int* in_sizes, int n_in,
                              void* d_out, int out_size, void* d_ws, size_t ws_size,
                              hipStream_t stream)
{
    const float* x       = (const float*)d_in[0];
    const int*   adj     = (const int*)  d_in[1];
    const float* W_enc   = (const float*)d_in[2];
    const float* b_enc   = (const float*)d_in[3];
    const float* cls_tok = (const float*)d_in[4];
    const float* pos_emb = (const float*)d_in[5];
    const float* Wq = (const float*)d_in[6];
    const float* bq = (const float*)d_in[7];
    const float* Wk = (const float*)d_in[8];
    const float* bk = (const float*)d_in[9];
    const float* Wv = (const float*)d_in[10];
    const float* bv = (const float*)d_in[11];
    const float* Wo = (const float*)d_in[12];
    const float* bo = (const float*)d_in[13];
    const float* W1 = (const float*)d_in[14];
    const float* b1 = (const float*)d_in[15];
    const float* W2 = (const float*)d_in[16];
    const float* b2 = (const float*)d_in[17];
    const float* g1 = (const float*)d_in[18];
    const float* be1= (const float*)d_in[19];
    const float* g2 = (const float*)d_in[20];
    const float* be2= (const float*)d_in[21];
    const float* Wd1= (const float*)d_in[22];
    const float* bd1= (const float*)d_in[23];
    const float* Wd2= (const float*)d_in[24];
    const float* bd2= (const float*)d_in[25];
    const float* Wg = (const float*)d_in[26];
    const float* ag = (const float*)d_in[27];
    const float* Wgo= (const float*)d_in[28];
    const float* ago= (const float*)d_in[29];
    float* out = (float*)d_out;

    // workspace layout (MP = 5248 padded rows):
    //   h, q, k, v : fp32 [MP][512]
    //   f1b (bf16 [MP][2048]) aliases k+v exactly (both 21.49 MB)
    //   hb, ob     : bf16 [MP][512]
    //   Wqt/Wkt/Wvt/Wot : bf16 [4][512][512] (transposed [N][K])
    //   W1t : bf16 [4][2048][512] ; W2t : bf16 [4][512][2048]
    // total ~78.9 MB
    float* ws = (float*)d_ws;
    float* h = ws;
    float* q = h + (size_t)MP * DM;
    float* k = q + (size_t)MP * DM;
    float* v = k + (size_t)MP * DM;
    unsigned short* f1b = (unsigned short*)k;               // aliases k,v
    unsigned short* hb  = (unsigned short*)(v + (size_t)MP * DM);
    unsigned short* ob  = hb + (size_t)MP * DM;
    unsigned short* Wqt = ob + (size_t)MP * DM;
    unsigned short* Wkt = Wqt + (size_t)4 * DM * DM;
    unsigned short* Wvt = Wkt + (size_t)4 * DM * DM;
    unsigned short* Wot = Wvt + (size_t)4 * DM * DM;
    unsigned short* W1t = Wot + (size_t)4 * DM * DM;
    unsigned short* W2t = W1t + (size_t)4 * DM * DFF;

    // Weight conversions (transpose + cast), one launch per weight array
    wconv_kernel<<<dim3(DM/32,  DM/32,  4), 256, 0, stream>>>(Wq, Wqt, DM,  DM);
    wconv_kernel<<<dim3(DM/32,  DM/32,  4), 256, 0, stream>>>(Wk, Wkt, DM,  DM);
    wconv_kernel<<<dim3(DM/32,  DM/32,  4), 256, 0, stream>>>(Wv, Wvt, DM,  DM);
    wconv_kernel<<<dim3(DM/32,  DM/32,  4), 256, 0, stream>>>(Wo, Wot, DM,  DM);
    wconv_kernel<<<dim3(DFF/32, DM/32,  4), 256, 0, stream>>>(W1, W1t, DM,  DFF);
    wconv_kernel<<<dim3(DM/32,  DFF/32, 4), 256, 0, stream>>>(W2, W2t, DFF, DM);

    gat_kernel<<<NGRAPH, 64, 0, stream>>>(x, adj, Wg, ag, Wgo, ago, out + NBATCH * NCLS);
    encoder_kernel<<<ROWS, 256, 0, stream>>>(x, W_enc, b_enc, cls_tok, pos_emb, h, hb);

    dim3 g512 (DM  / 128, MP / 128);   // (4, 41)
    dim3 g2048(DFF / 128, MP / 128);   // (16, 41)
    dim3 gAttn((T + AQ - 1) / AQ, NBATCH * NHEAD);

    for (int i = 0; i < 4; ++i) {
        gemm_mfma<<<g512, 256, 0, stream>>>(hb, Wqt + (size_t)i*DM*DM, bq + i*DM, q, nullptr, DM, DM, 0);
        gemm_mfma<<<g512, 256, 0, stream>>>(hb, Wkt + (size_t)i*DM*DM, bk + i*DM, k, nullptr, DM, DM, 0);
        gemm_mfma<<<g512, 256, 0, stream>>>(hb, Wvt + (size_t)i*DM*DM, bv + i*DM, v, nullptr, DM, DM, 0);
        attn_kernel<<<gAttn, 256, 0, stream>>>(q, k, v, ob);
        gemm_mfma<<<g512, 256, 0, stream>>>(ob, Wot + (size_t)i*DM*DM, bo + i*DM, q, nullptr, DM, DM, 0);
        add_ln_kernel<<<ROWS, 256, 0, stream>>>(h, q, g1 + i*DM, be1 + i*DM, hb);
        gemm_mfma<<<g2048, 256, 0, stream>>>(hb,  W1t + (size_t)i*DM*DFF, b1 + i*DFF, nullptr, f1b, DFF, DM, 1);
        gemm_mfma<<<g512, 256, 0, stream>>>(f1b, W2t + (size_t)i*DM*DFF, b2 + i*DM,  q, nullptr, DM, DFF, 0);
        add_ln_kernel<<<ROWS, 256, 0, stream>>>(h, q, g2 + i*DM, be2 + i*DM, hb);
    }

    decoder_kernel<<<1, 256, 0, stream>>>(h, Wd1, bd1, Wd2, bd2, out);
}

// Round 4
// 1212.605 us; speedup vs baseline: 11.5537x; 1.4151x over previous
//
#include <hip/hip_runtime.h>
#include <hip/hip_bf16.h>
#include <math.h>

// ---------------------------------------------------------------------------
// Model constants
// ---------------------------------------------------------------------------
#define NBATCH 5
#define SEQ    1024
#define T      1025          // SEQ + 1 (cls token)
#define ROWS   (NBATCH * T)  // 5125
#define MP     5248          // ROWS padded to 41*128 for MFMA tiles
#define DM     512
#define DFF    2048
#define NHEAD  8
#define HD     64
#define NTOK   51
#define MLPDIM 256
#define NCLS   7
#define GH     3
#define GHID   64
#define GCLS   5
#define NGRAPH (SEQ * 5)     // 5120

typedef __attribute__((ext_vector_type(8))) short bf16x8;
typedef __attribute__((ext_vector_type(4))) float f32x4;

#define GM_AS(p)  ((const __attribute__((address_space(1))) void*)(p))
#define LDS_AS(p) ((__attribute__((address_space(3))) void*)(p))

__device__ __forceinline__ unsigned short f2bf(float f) {
    unsigned int u = __float_as_uint(f);
    unsigned int r = (u + 0x7FFFu + ((u >> 16) & 1u)) >> 16;
    return (unsigned short)r;
}

// ---------------------------------------------------------------------------
// Weight transpose + fp32->bf16: W[K][N] (per mat) -> Wt[N][K]. blockIdx.z = mat.
// ---------------------------------------------------------------------------
__global__ __launch_bounds__(256) void wconv_kernel(
    const float* __restrict__ W, unsigned short* __restrict__ Wt, int K, int N)
{
    const float* Wm = W + (size_t)blockIdx.z * K * N;
    unsigned short* Wo = Wt + (size_t)blockIdx.z * K * N;
    __shared__ float tile[32][33];
    int bx = blockIdx.x * 32;   // N dir
    int by = blockIdx.y * 32;   // K dir
    int tx = threadIdx.x & 31, ty = threadIdx.x >> 5;   // 32 x 8
    #pragma unroll
    for (int i = 0; i < 32; i += 8)
        tile[ty + i][tx] = Wm[(size_t)(by + ty + i) * N + bx + tx];
    __syncthreads();
    #pragma unroll
    for (int i = 0; i < 32; i += 8)
        Wo[(size_t)(bx + ty + i) * K + by + tx] = f2bf(tile[tx][ty + i]);
}

// ---------------------------------------------------------------------------
// bf16 MFMA GEMM (m97 structure): C[M][N] = A[M][K] @ Bt[N][K]^T + bias.
// 128x128 block tile, BK=32, 256 threads = 4 waves in 2x2, each wave 64x64.
// ---------------------------------------------------------------------------
__global__ __launch_bounds__(256) void gemm_mfma(
    const unsigned short* __restrict__ A, const unsigned short* __restrict__ Bt,
    const float* __restrict__ bias, float* __restrict__ Cf,
    unsigned short* __restrict__ Cb, int N, int K, int relu)
{
    __shared__ unsigned short As[128 * 32];
    __shared__ unsigned short Bs[128 * 32];
    int tid = threadIdx.x;
    int l = tid & 63, w = tid >> 6;
    int wr = w & 1, wc = w >> 1;
    int mlane = l & 15, quad = l >> 4;
    int m0 = blockIdx.y * 128, n0 = blockIdx.x * 128;

    f32x4 acc[4][4] = {};   // [mi][ni]

    for (int k0 = 0; k0 < K; k0 += 32) {
        __syncthreads();
        #pragma unroll
        for (int it = 0; it < 2; ++it) {
            int c = tid + it * 256;          // 16B chunk id, 4 chunks/row
            int row = c >> 2, cc = c & 3;
            const unsigned short* ga = A  + (size_t)(m0 + row) * K + k0 + cc * 8;
            __builtin_amdgcn_global_load_lds(GM_AS(ga), LDS_AS(As + c * 8), 16, 0, 0);
            const unsigned short* gb = Bt + (size_t)(n0 + row) * K + k0 + cc * 8;
            __builtin_amdgcn_global_load_lds(GM_AS(gb), LDS_AS(Bs + c * 8), 16, 0, 0);
        }
        __syncthreads();
        bf16x8 afrag[4], bfrag[4];
        #pragma unroll
        for (int mi = 0; mi < 4; ++mi)
            afrag[mi] = *(const bf16x8*)(As + (wr * 64 + mi * 16 + mlane) * 32 + quad * 8);
        #pragma unroll
        for (int ni = 0; ni < 4; ++ni)
            bfrag[ni] = *(const bf16x8*)(Bs + (wc * 64 + ni * 16 + mlane) * 32 + quad * 8);
        #pragma unroll
        for (int mi = 0; mi < 4; ++mi)
            #pragma unroll
            for (int ni = 0; ni < 4; ++ni)
                acc[mi][ni] = __builtin_amdgcn_mfma_f32_16x16x32_bf16(
                    afrag[mi], bfrag[ni], acc[mi][ni], 0, 0, 0);
    }

    // C/D layout: col = lane&15, row = quad*4 + reg
    #pragma unroll
    for (int mi = 0; mi < 4; ++mi) {
        #pragma unroll
        for (int r = 0; r < 4; ++r) {
            int gm = m0 + wr * 64 + mi * 16 + quad * 4 + r;
            size_t rowoff = (size_t)gm * N;
            #pragma unroll
            for (int ni = 0; ni < 4; ++ni) {
                int gn = n0 + wc * 64 + ni * 16 + mlane;
                float val = acc[mi][ni][r] + bias[gn];
                if (relu) val = fmaxf(val, 0.f);
                if (Cb) Cb[rowoff + gn] = f2bf(val);
                else    Cf[rowoff + gn] = val;
            }
        }
    }
}

// ---------------------------------------------------------------------------
// bf16 MFMA flash attention. Block = 128 queries x (b,h); 4 waves, each 32 q.
// Keys in 64-chunks: K staged [key][72] (natural), V staged transposed [d][72].
// S = Q K^T (MFMA), online softmax (fp32 regs + 16-lane shfl), P -> wave-
// private LDS -> A-frags, O += P V (MFMA). All LDS strides 72 (4-bank skew).
// ---------------------------------------------------------------------------
#define AQT 128
__global__ __launch_bounds__(256) void attn_mfma(
    const unsigned short* __restrict__ qb, const unsigned short* __restrict__ kb,
    const unsigned short* __restrict__ vb, unsigned short* __restrict__ ob)
{
    __shared__ unsigned short Ks[64 * 72];
    __shared__ unsigned short Vt[64 * 72];
    __shared__ unsigned short Ps[4][32 * 72];
    int bh = blockIdx.y;
    int b = bh >> 3, h = bh & 7;
    int t0 = blockIdx.x * AQT;
    int tid = threadIdx.x;
    int l = tid & 63, w = tid >> 6;
    int ml = l & 15, quad = l >> 4;
    size_t rowbase = (size_t)b * T;

    // Q fragments, held for the whole kernel (A-operand layout)
    bf16x8 qf[2][2];
    #pragma unroll
    for (int mi = 0; mi < 2; ++mi) {
        int qrow = t0 + w * 32 + mi * 16 + ml;
        if (qrow >= T) qrow = T - 1;
        const unsigned short* qp = qb + (rowbase + qrow) * DM + h * HD + quad * 8;
        qf[mi][0] = *(const bf16x8*)qp;
        qf[mi][1] = *(const bf16x8*)(qp + 32);
    }

    f32x4 oacc[2][4] = {};       // [mi][ni], rows quad*4+r, cols d=ni*16+ml
    float mrow[2][4], lrow[2][4];
    #pragma unroll
    for (int mi = 0; mi < 2; ++mi)
        #pragma unroll
        for (int r = 0; r < 4; ++r) { mrow[mi][r] = -1e30f; lrow[mi][r] = 0.f; }

    for (int c0 = 0; c0 < T; c0 += 64) {
        __syncthreads();
        // stage K chunk: Ks[key][72], d contiguous
        #pragma unroll
        for (int it = 0; it < 2; ++it) {
            int c = tid + it * 256;            // 512 x 16B
            int key = c >> 3, cc = c & 7;
            bf16x8 kv = *(const bf16x8*)(kb + (rowbase + c0 + key) * DM + h * HD + cc * 8);
            *(bf16x8*)(Ks + key * 72 + cc * 8) = kv;
        }
        // stage V^T chunk: Vt[d][72], key contiguous
        #pragma unroll
        for (int it = 0; it < 4; ++it) {
            int c = tid + it * 256;            // 1024 x ushort4
            int key = c >> 4, cc = c & 15;
            ushort4 vv = *(const ushort4*)(vb + (rowbase + c0 + key) * DM + h * HD + cc * 4);
            Vt[(cc * 4 + 0) * 72 + key] = vv.x;
            Vt[(cc * 4 + 1) * 72 + key] = vv.y;
            Vt[(cc * 4 + 2) * 72 + key] = vv.z;
            Vt[(cc * 4 + 3) * 72 + key] = vv.w;
        }
        __syncthreads();

        // S = Q K^T
        f32x4 s[2][4] = {};
        #pragma unroll
        for (int ni = 0; ni < 4; ++ni) {
            bf16x8 kf0 = *(const bf16x8*)(Ks + (ni * 16 + ml) * 72 + quad * 8);
            bf16x8 kf1 = *(const bf16x8*)(Ks + (ni * 16 + ml) * 72 + 32 + quad * 8);
            #pragma unroll
            for (int mi = 0; mi < 2; ++mi) {
                s[mi][ni] = __builtin_amdgcn_mfma_f32_16x16x32_bf16(qf[mi][0], kf0, s[mi][ni], 0, 0, 0);
                s[mi][ni] = __builtin_amdgcn_mfma_f32_16x16x32_bf16(qf[mi][1], kf1, s[mi][ni], 0, 0, 0);
            }
        }
        // scale + mask invalid keys
        #pragma unroll
        for (int ni = 0; ni < 4; ++ni) {
            bool valid = (c0 + ni * 16 + ml) < T;
            #pragma unroll
            for (int mi = 0; mi < 2; ++mi)
                #pragma unroll
                for (int r = 0; r < 4; ++r)
                    s[mi][ni][r] = valid ? s[mi][ni][r] * 0.125f : -1e30f;
        }
        // online softmax per row (rows = quad*4+r, reduce over 16 lanes + ni)
        #pragma unroll
        for (int mi = 0; mi < 2; ++mi) {
            #pragma unroll
            for (int r = 0; r < 4; ++r) {
                float mx = fmaxf(fmaxf(s[mi][0][r], s[mi][1][r]),
                                 fmaxf(s[mi][2][r], s[mi][3][r]));
                #pragma unroll
                for (int off = 1; off < 16; off <<= 1)
                    mx = fmaxf(mx, __shfl_xor(mx, off));
                float mnew = fmaxf(mrow[mi][r], mx);
                float alpha = __expf(mrow[mi][r] - mnew);
                mrow[mi][r] = mnew;
                float rs = 0.f;
                #pragma unroll
                for (int ni = 0; ni < 4; ++ni) {
                    float p = __expf(s[mi][ni][r] - mnew);
                    s[mi][ni][r] = p; rs += p;
                }
                #pragma unroll
                for (int off = 1; off < 16; off <<= 1)
                    rs += __shfl_xor(rs, off);
                lrow[mi][r] = lrow[mi][r] * alpha + rs;
                #pragma unroll
                for (int ni = 0; ni < 4; ++ni) oacc[mi][ni][r] *= alpha;
            }
        }
        // P -> wave-private LDS (bf16), [q 0..31][key 0..63], stride 72
        unsigned short* pw = Ps[w];
        #pragma unroll
        for (int mi = 0; mi < 2; ++mi)
            #pragma unroll
            for (int r = 0; r < 4; ++r)
                #pragma unroll
                for (int ni = 0; ni < 4; ++ni)
                    pw[(mi * 16 + quad * 4 + r) * 72 + ni * 16 + ml] = f2bf(s[mi][ni][r]);
        // O += P V   (wave-private Ps: no barrier needed)
        #pragma unroll
        for (int kc = 0; kc < 2; ++kc) {
            bf16x8 pf[2];
            pf[0] = *(const bf16x8*)(pw + (ml) * 72 + kc * 32 + quad * 8);
            pf[1] = *(const bf16x8*)(pw + (16 + ml) * 72 + kc * 32 + quad * 8);
            #pragma unroll
            for (int ni = 0; ni < 4; ++ni) {
                bf16x8 vf = *(const bf16x8*)(Vt + (ni * 16 + ml) * 72 + kc * 32 + quad * 8);
                #pragma unroll
                for (int mi = 0; mi < 2; ++mi)
                    oacc[mi][ni] = __builtin_amdgcn_mfma_f32_16x16x32_bf16(pf[mi], vf, oacc[mi][ni], 0, 0, 0);
            }
        }
    }

    // epilogue: O / l, write bf16
    #pragma unroll
    for (int mi = 0; mi < 2; ++mi) {
        #pragma unroll
        for (int r = 0; r < 4; ++r) {
            int grow = t0 + w * 32 + mi * 16 + quad * 4 + r;
            if (grow >= T) continue;
            float inv = 1.f / lrow[mi][r];
            unsigned short* op = ob + (rowbase + grow) * DM + h * HD;
            #pragma unroll
            for (int ni = 0; ni < 4; ++ni)
                op[ni * 16 + ml] = f2bf(oacc[mi][ni][r] * inv);
        }
    }
}

// ---------------------------------------------------------------------------
// Encoder: writes fp32 h and bf16 shadow hb
// ---------------------------------------------------------------------------
__global__ __launch_bounds__(256) void encoder_kernel(
    const float* __restrict__ x, const float* __restrict__ W_enc,
    const float* __restrict__ b_enc, const float* __restrict__ cls_tok,
    const float* __restrict__ pos_emb, float* __restrict__ h,
    unsigned short* __restrict__ hb)
{
    int row = blockIdx.x;
    int b = row / T, tt = row % T;
    int tid = threadIdx.x;
    float* hp = h + (size_t)row * DM;
    unsigned short* hbp = hb + (size_t)row * DM;
    if (tt == 0) {
        float a0 = cls_tok[tid]       + pos_emb[tid];
        float a1 = cls_tok[tid + 256] + pos_emb[tid + 256];
        hp[tid] = a0; hp[tid + 256] = a1;
        hbp[tid] = f2bf(a0); hbp[tid + 256] = f2bf(a1);
        return;
    }
    __shared__ float xs[NTOK];
    int s = tt - 1;
    if (tid < NTOK) xs[tid] = x[((size_t)b * SEQ + s) * NTOK + tid];
    __syncthreads();
    #pragma unroll
    for (int rep = 0; rep < 2; ++rep) {
        int d = tid + rep * 256;
        float acc = b_enc[d] + pos_emb[(size_t)tt * DM + d];
        for (int kx = 0; kx < NTOK; ++kx) acc += xs[kx] * W_enc[kx * DM + d];
        hp[d] = acc;
        hbp[d] = f2bf(acc);
    }
}

// ---------------------------------------------------------------------------
// Fused residual + LayerNorm: h = LN(h + r)*g + be; writes bf16 shadow hb
// ---------------------------------------------------------------------------
__global__ __launch_bounds__(256) void add_ln_kernel(
    float* __restrict__ h, const float* __restrict__ r,
    const float* __restrict__ g, const float* __restrict__ be,
    unsigned short* __restrict__ hb)
{
    int row = blockIdx.x;
    int tid = threadIdx.x;
    float* hp = h + (size_t)row * DM;
    unsigned short* hbp = hb + (size_t)row * DM;
    const float* rp = r + (size_t)row * DM;
    __shared__ float red[256];
    float v0 = hp[tid] + rp[tid];
    float v1 = hp[tid + 256] + rp[tid + 256];
    red[tid] = v0 + v1; __syncthreads();
    for (int st = 128; st > 0; st >>= 1) {
        if (tid < st) red[tid] += red[tid + st];
        __syncthreads();
    }
    float mean = red[0] * (1.f / DM);
    __syncthreads();
    float d0 = v0 - mean, d1 = v1 - mean;
    red[tid] = d0 * d0 + d1 * d1; __syncthreads();
    for (int st = 128; st > 0; st >>= 1) {
        if (tid < st) red[tid] += red[tid + st];
        __syncthreads();
    }
    float inv = rsqrtf(red[0] * (1.f / DM) + 1e-5f);
    float o0 = d0 * inv * g[tid]       + be[tid];
    float o1 = d1 * inv * g[tid + 256] + be[tid + 256];
    hp[tid] = o0; hp[tid + 256] = o1;
    hbp[tid] = f2bf(o0); hbp[tid + 256] = f2bf(o1);
}

// ---------------------------------------------------------------------------
// Decoder head
// ---------------------------------------------------------------------------
__global__ __launch_bounds__(256) void decoder_kernel(
    const float* __restrict__ h, const float* __restrict__ Wd1,
    const float* __restrict__ bd1, const float* __restrict__ Wd2,
    const float* __restrict__ bd2, float* __restrict__ out)
{
    __shared__ float t1s[MLPDIM];
    int tid = threadIdx.x;
    for (int b = 0; b < NBATCH; ++b) {
        const float* cls = h + (size_t)b * T * DM;
        float acc = bd1[tid];
        for (int kx = 0; kx < DM; ++kx) acc += cls[kx] * Wd1[kx * MLPDIM + tid];
        t1s[tid] = acc;
        __syncthreads();
        if (tid < NCLS) {
            float a2 = bd2[tid];
            for (int kx = 0; kx < MLPDIM; ++kx) a2 += t1s[kx] * Wd2[kx * NCLS + tid];
            out[b * NCLS + tid] = a2;
        }
        __syncthreads();
    }
}

// ---------------------------------------------------------------------------
// GAT (unchanged)
// ---------------------------------------------------------------------------
__global__ __launch_bounds__(64) void gat_kernel(
    const float* __restrict__ x, const int* __restrict__ adj,
    const float* __restrict__ Wg, const float* __restrict__ ag,
    const float* __restrict__ Wgo, const float* __restrict__ ago,
    float* __restrict__ out)
{
    int g = blockIdx.x;
    int s = g / 5, jj = g % 5;
    int tid = threadIdx.x;
    __shared__ float xs[5][3];
    __shared__ int adjs[25];
    __shared__ float hb[GH][5][GHID];
    __shared__ float o1[GH][5][GHID];
    __shared__ float srcb[GH][5], dstb[GH][5];
    __shared__ float attb[GH][5][5];
    __shared__ float h2[5][5], src2[5], dst2[5], att2[5][5], o2[5][5];

    if (tid < 15) { int n = tid / 3, c = tid % 3;
        xs[n][c] = x[(size_t)n * SEQ * NTOK + (size_t)s * NTOK + jj * 3 + c]; }
    if (tid < 25) adjs[tid] = adj[tid];
    __syncthreads();

    #pragma unroll
    for (int hh = 0; hh < GH; ++hh)
        #pragma unroll
        for (int n = 0; n < 5; ++n)
            hb[hh][n][tid] = xs[n][0] * Wg[hh * 192 + tid]
                           + xs[n][1] * Wg[hh * 192 + 64 + tid]
                           + xs[n][2] * Wg[hh * 192 + 128 + tid];
    __syncthreads();

    if (tid < 15) { int hh = tid / 5, n = tid % 5; float a = 0.f;
        for (int f = 0; f < GHID; ++f) a += hb[hh][n][f] * ag[hh * 128 + f];
        srcb[hh][n] = a;
    } else if (tid >= 32 && tid < 47) { int t2 = tid - 32; int hh = t2 / 5, n = t2 % 5; float a = 0.f;
        for (int f = 0; f < GHID; ++f) a += hb[hh][n][f] * ag[hh * 128 + 64 + f];
        dstb[hh][n] = a;
    }
    __syncthreads();

    if (tid < 15) { int hh = tid / 5, i = tid % 5;
        float e[5]; float mx = -1e30f;
        #pragma unroll
        for (int j2 = 0; j2 < 5; ++j2) {
            float ev = srcb[hh][i] + dstb[hh][j2];
            ev = ev > 0.f ? ev : 0.2f * ev;
            e[j2] = ev;
            if (adjs[i * 5 + j2] && ev > mx) mx = ev;
        }
        float sum = 0.f;
        #pragma unroll
        for (int j2 = 0; j2 < 5; ++j2) {
            float p = adjs[i * 5 + j2] ? expf(e[j2] - mx) : 0.f;
            e[j2] = p; sum += p;
        }
        float inv = 1.f / sum;
        #pragma unroll
        for (int j2 = 0; j2 < 5; ++j2) attb[hh][i][j2] = e[j2] * inv;
    }
    __syncthreads();

    #pragma unroll
    for (int hh = 0; hh < GH; ++hh)
        #pragma unroll
        for (int n = 0; n < 5; ++n) {
            float a = 0.f;
            #pragma unroll
            for (int j2 = 0; j2 < 5; ++j2) a += attb[hh][n][j2] * hb[hh][j2][tid];
            o1[hh][n][tid] = a > 0.f ? a : expm1f(a);
        }
    __syncthreads();

    if (tid < 25) { int n = tid / 5, m = tid % 5; float a = 0.f;
        for (int hh = 0; hh < GH; ++hh)
            for (int f = 0; f < GHID; ++f)
                a += o1[hh][n][f] * Wgo[(hh * GHID + f) * GCLS + m];
        h2[n][m] = a;
    }
    __syncthreads();

    if (tid < 5) { float a = 0.f;
        for (int m = 0; m < GCLS; ++m) a += h2[tid][m] * ago[m];
        src2[tid] = a;
    } else if (tid >= 8 && tid < 13) { int n = tid - 8; float a = 0.f;
        for (int m = 0; m < GCLS; ++m) a += h2[n][m] * ago[GCLS + m];
        dst2[n] = a;
    }
    __syncthreads();

    if (tid < 5) { int i = tid;
        float e[5]; float mx = -1e30f;
        #pragma unroll
        for (int j2 = 0; j2 < 5; ++j2) {
            float ev = src2[i] + dst2[j2];
            ev = ev > 0.f ? ev : 0.2f * ev;
            e[j2] = ev;
            if (adjs[i * 5 + j2] && ev > mx) mx = ev;
        }
        float sum = 0.f;
        #pragma unroll
        for (int j2 = 0; j2 < 5; ++j2) {
            float p = adjs[i * 5 + j2] ? expf(e[j2] - mx) : 0.f;
            e[j2] = p; sum += p;
        }
        float inv = 1.f / sum;
        #pragma unroll
        for (int j2 = 0; j2 < 5; ++j2) att2[i][j2] = e[j2] * inv;
    }
    __syncthreads();

    if (tid < 25) { int n = tid / 5, m = tid % 5; float a = 0.f;
        #pragma unroll
        for (int j2 = 0; j2 < 5; ++j2) a += att2[n][j2] * h2[j2][m];
        o2[n][m] = a > 0.f ? a : expm1f(a);
    }
    __syncthreads();

    if (tid < 5) { int n = tid;
        float mx = o2[n][0];
        #pragma unroll
        for (int m = 1; m < GCLS; ++m) mx = fmaxf(mx, o2[n][m]);
        float sum = 0.f;
        #pragma unroll
        for (int m = 0; m < GCLS; ++m) sum += expf(o2[n][m] - mx);
        float ls = logf(sum);
        #pragma unroll
        for (int m = 0; m < GCLS; ++m)
            out[(size_t)g * 25 + n * 5 + m] = o2[n][m] - mx - ls;
    }
}

// ---------------------------------------------------------------------------
// Launch
// ---------------------------------------------------------------------------
extern "C" void kernel_launch(void* const* d_in, const int* in_sizes, int n_in,
                              void* d_out, int out_size, void* d_ws, size_t ws_size,
                              hipStream_t stream)
{
    const float* x       = (const float*)d_in[0];
    const int*   adj     = (const int*)  d_in[1];
    const float* W_enc   = (const float*)d_in[2];
    const float* b_enc   = (const float*)d_in[3];
    const float* cls_tok = (const float*)d_in[4];
    const float* pos_emb = (const float*)d_in[5];
    const float* Wq = (const float*)d_in[6];
    const float* bq = (const float*)d_in[7];
    const float* Wk = (const float*)d_in[8];
    const float* bk = (const float*)d_in[9];
    const float* Wv = (const float*)d_in[10];
    const float* bv = (const float*)d_in[11];
    const float* Wo = (const float*)d_in[12];
    const float* bo = (const float*)d_in[13];
    const float* W1 = (const float*)d_in[14];
    const float* b1 = (const float*)d_in[15];
    const float* W2 = (const float*)d_in[16];
    const float* b2 = (const float*)d_in[17];
    const float* g1 = (const float*)d_in[18];
    const float* be1= (const float*)d_in[19];
    const float* g2 = (const float*)d_in[20];
    const float* be2= (const float*)d_in[21];
    const float* Wd1= (const float*)d_in[22];
    const float* bd1= (const float*)d_in[23];
    const float* Wd2= (const float*)d_in[24];
    const float* bd2= (const float*)d_in[25];
    const float* Wg = (const float*)d_in[26];
    const float* ag = (const float*)d_in[27];
    const float* Wgo= (const float*)d_in[28];
    const float* ago= (const float*)d_in[29];
    float* out = (float*)d_out;

    // workspace layout (MP = 5248 padded rows):
    //   h, q : fp32 [MP][512]
    //   hb   : bf16 [MP][512]
    //   qb|kb|vb|ob : bf16 [MP][512] each; f1b (bf16 [MP][2048]) aliases all 4
    //     (qb/kb/vb dead after attn, ob dead after Wo gemm, then f1b written)
    //   Wt weights: bf16 transposed [N][K]
    float* ws = (float*)d_ws;
    float* h = ws;
    float* q = h + (size_t)MP * DM;
    unsigned short* hb  = (unsigned short*)(q + (size_t)MP * DM);
    unsigned short* qb  = hb + (size_t)MP * DM;
    unsigned short* kb  = qb + (size_t)MP * DM;
    unsigned short* vb  = kb + (size_t)MP * DM;
    unsigned short* ob  = vb + (size_t)MP * DM;
    unsigned short* f1b = qb;                       // alias qb..ob
    unsigned short* Wqt = ob + (size_t)MP * DM;
    unsigned short* Wkt = Wqt + (size_t)4 * DM * DM;
    unsigned short* Wvt = Wkt + (size_t)4 * DM * DM;
    unsigned short* Wot = Wvt + (size_t)4 * DM * DM;
    unsigned short* W1t = Wot + (size_t)4 * DM * DM;
    unsigned short* W2t = W1t + (size_t)4 * DM * DFF;

    wconv_kernel<<<dim3(DM/32,  DM/32,  4), 256, 0, stream>>>(Wq, Wqt, DM,  DM);
    wconv_kernel<<<dim3(DM/32,  DM/32,  4), 256, 0, stream>>>(Wk, Wkt, DM,  DM);
    wconv_kernel<<<dim3(DM/32,  DM/32,  4), 256, 0, stream>>>(Wv, Wvt, DM,  DM);
    wconv_kernel<<<dim3(DM/32,  DM/32,  4), 256, 0, stream>>>(Wo, Wot, DM,  DM);
    wconv_kernel<<<dim3(DFF/32, DM/32,  4), 256, 0, stream>>>(W1, W1t, DM,  DFF);
    wconv_kernel<<<dim3(DM/32,  DFF/32, 4), 256, 0, stream>>>(W2, W2t, DFF, DM);

    gat_kernel<<<NGRAPH, 64, 0, stream>>>(x, adj, Wg, ag, Wgo, ago, out + NBATCH * NCLS);
    encoder_kernel<<<ROWS, 256, 0, stream>>>(x, W_enc, b_enc, cls_tok, pos_emb, h, hb);

    dim3 g512 (DM  / 128, MP / 128);   // (4, 41)
    dim3 g2048(DFF / 128, MP / 128);   // (16, 41)
    dim3 gAttn((T + AQT - 1) / AQT, NBATCH * NHEAD);  // (9, 40)

    for (int i = 0; i < 4; ++i) {
        gemm_mfma<<<g512, 256, 0, stream>>>(hb, Wqt + (size_t)i*DM*DM, bq + i*DM, nullptr, qb, DM, DM, 0);
        gemm_mfma<<<g512, 256, 0, stream>>>(hb, Wkt + (size_t)i*DM*DM, bk + i*DM, nullptr, kb, DM, DM, 0);
        gemm_mfma<<<g512, 256, 0, stream>>>(hb, Wvt + (size_t)i*DM*DM, bv + i*DM, nullptr, vb, DM, DM, 0);
        attn_mfma<<<gAttn, 256, 0, stream>>>(qb, kb, vb, ob);
        gemm_mfma<<<g512, 256, 0, stream>>>(ob, Wot + (size_t)i*DM*DM, bo + i*DM, q, nullptr, DM, DM, 0);
        add_ln_kernel<<<ROWS, 256, 0, stream>>>(h, q, g1 + i*DM, be1 + i*DM, hb);
        gemm_mfma<<<g2048, 256, 0, stream>>>(hb,  W1t + (size_t)i*DM*DFF, b1 + i*DFF, nullptr, f1b, DFF, DM, 1);
        gemm_mfma<<<g512, 256, 0, stream>>>(f1b, W2t + (size_t)i*DM*DFF, b2 + i*DM,  q, nullptr, DM, DFF, 0);
        add_ln_kernel<<<ROWS, 256, 0, stream>>>(h, q, g2 + i*DM, be2 + i*DM, hb);
    }

    decoder_kernel<<<1, 256, 0, stream>>>(h, Wd1, bd1, Wd2, bd2, out);
}

// Round 5
// 1038.671 us; speedup vs baseline: 13.4885x; 1.1675x over previous
//
#include <hip/hip_runtime.h>
#include <hip/hip_bf16.h>
#include <math.h>

// ---------------------------------------------------------------------------
// Model constants
// ---------------------------------------------------------------------------
#define NBATCH 5
#define SEQ    1024
#define T      1025          // SEQ + 1 (cls token)
#define ROWS   (NBATCH * T)  // 5125
#define MP     5248          // ROWS padded to 41*128 for MFMA tiles
#define DM     512
#define DFF    2048
#define NHEAD  8
#define HD     64
#define NTOK   51
#define MLPDIM 256
#define NCLS   7
#define GH     3
#define GHID   64
#define GCLS   5
#define NGRAPH (SEQ * 5)     // 5120
#define QKVN   1536          // fused QKV output width

typedef __attribute__((ext_vector_type(8))) short bf16x8;
typedef __attribute__((ext_vector_type(4))) float f32x4;

#define GM_AS(p)  ((const __attribute__((address_space(1))) void*)(p))
#define LDS_AS(p) ((__attribute__((address_space(3))) void*)(p))

__device__ __forceinline__ unsigned short f2bf(float f) {
    unsigned int u = __float_as_uint(f);
    unsigned int r = (u + 0x7FFFu + ((u >> 16) & 1u)) >> 16;
    return (unsigned short)r;
}

// ---------------------------------------------------------------------------
// Weight transpose + fp32->bf16: W[K][N] (mat z at z*K*N) -> Wt (at z*dstride),
// layout [N][K]. dstride lets us interleave Wq/Wk/Wv per layer.
// ---------------------------------------------------------------------------
__global__ __launch_bounds__(256) void wconv_kernel(
    const float* __restrict__ W, unsigned short* __restrict__ Wt, int K, int N,
    long dstride)
{
    const float* Wm = W + (size_t)blockIdx.z * K * N;
    unsigned short* Wo = Wt + (size_t)blockIdx.z * dstride;
    __shared__ float tile[32][33];
    int bx = blockIdx.x * 32;   // N dir
    int by = blockIdx.y * 32;   // K dir
    int tx = threadIdx.x & 31, ty = threadIdx.x >> 5;   // 32 x 8
    #pragma unroll
    for (int i = 0; i < 32; i += 8)
        tile[ty + i][tx] = Wm[(size_t)(by + ty + i) * N + bx + tx];
    __syncthreads();
    #pragma unroll
    for (int i = 0; i < 32; i += 8)
        Wo[(size_t)(bx + ty + i) * K + by + tx] = f2bf(tile[tx][ty + i]);
}

// Concat per-layer biases bq|bk|bv -> bqkv[L][1536]
__global__ __launch_bounds__(512) void bconcat_kernel(
    const float* __restrict__ bq, const float* __restrict__ bk,
    const float* __restrict__ bv, float* __restrict__ bqkv)
{
    int i = blockIdx.x, t = threadIdx.x;
    bqkv[i * QKVN + t]        = bq[i * DM + t];
    bqkv[i * QKVN + 512 + t]  = bk[i * DM + t];
    bqkv[i * QKVN + 1024 + t] = bv[i * DM + t];
}

// ---------------------------------------------------------------------------
// bf16 MFMA GEMM (m97 structure): C[M][N] = A[M][K] @ Bt[N][K]^T + bias.
// 128x128 block tile, BK=32, 256 threads = 4 waves in 2x2, each wave 64x64.
// ---------------------------------------------------------------------------
__global__ __launch_bounds__(256) void gemm_mfma(
    const unsigned short* __restrict__ A, const unsigned short* __restrict__ Bt,
    const float* __restrict__ bias, float* __restrict__ Cf,
    unsigned short* __restrict__ Cb, int N, int K, int relu)
{
    __shared__ unsigned short As[128 * 32];
    __shared__ unsigned short Bs[128 * 32];
    int tid = threadIdx.x;
    int l = tid & 63, w = tid >> 6;
    int wr = w & 1, wc = w >> 1;
    int mlane = l & 15, quad = l >> 4;
    int m0 = blockIdx.y * 128, n0 = blockIdx.x * 128;

    f32x4 acc[4][4] = {};   // [mi][ni]

    for (int k0 = 0; k0 < K; k0 += 32) {
        __syncthreads();
        #pragma unroll
        for (int it = 0; it < 2; ++it) {
            int c = tid + it * 256;          // 16B chunk id, 4 chunks/row
            int row = c >> 2, cc = c & 3;
            const unsigned short* ga = A  + (size_t)(m0 + row) * K + k0 + cc * 8;
            __builtin_amdgcn_global_load_lds(GM_AS(ga), LDS_AS(As + c * 8), 16, 0, 0);
            const unsigned short* gb = Bt + (size_t)(n0 + row) * K + k0 + cc * 8;
            __builtin_amdgcn_global_load_lds(GM_AS(gb), LDS_AS(Bs + c * 8), 16, 0, 0);
        }
        __syncthreads();
        bf16x8 afrag[4], bfrag[4];
        #pragma unroll
        for (int mi = 0; mi < 4; ++mi)
            afrag[mi] = *(const bf16x8*)(As + (wr * 64 + mi * 16 + mlane) * 32 + quad * 8);
        #pragma unroll
        for (int ni = 0; ni < 4; ++ni)
            bfrag[ni] = *(const bf16x8*)(Bs + (wc * 64 + ni * 16 + mlane) * 32 + quad * 8);
        #pragma unroll
        for (int mi = 0; mi < 4; ++mi)
            #pragma unroll
            for (int ni = 0; ni < 4; ++ni)
                acc[mi][ni] = __builtin_amdgcn_mfma_f32_16x16x32_bf16(
                    afrag[mi], bfrag[ni], acc[mi][ni], 0, 0, 0);
    }

    // C/D layout: col = lane&15, row = quad*4 + reg
    #pragma unroll
    for (int mi = 0; mi < 4; ++mi) {
        #pragma unroll
        for (int r = 0; r < 4; ++r) {
            int gm = m0 + wr * 64 + mi * 16 + quad * 4 + r;
            size_t rowoff = (size_t)gm * N;
            #pragma unroll
            for (int ni = 0; ni < 4; ++ni) {
                int gn = n0 + wc * 64 + ni * 16 + mlane;
                float val = acc[mi][ni][r] + bias[gn];
                if (relu) val = fmaxf(val, 0.f);
                if (Cb) Cb[rowoff + gn] = f2bf(val);
                else    Cf[rowoff + gn] = val;
            }
        }
    }
}

// ---------------------------------------------------------------------------
// bf16 MFMA flash attention. Block = 128 queries x (b,h); 4 waves, each 32 q.
// q/k/v read from the fused qkv buffer with row stride qs (=1536).
// ---------------------------------------------------------------------------
#define AQT 128
__global__ __launch_bounds__(256) void attn_mfma(
    const unsigned short* __restrict__ qb, const unsigned short* __restrict__ kb,
    const unsigned short* __restrict__ vb, unsigned short* __restrict__ ob,
    int qs)
{
    __shared__ unsigned short Ks[64 * 72];
    __shared__ unsigned short Vt[64 * 72];
    __shared__ unsigned short Ps[4][32 * 72];
    int bh = blockIdx.y;
    int b = bh >> 3, h = bh & 7;
    int t0 = blockIdx.x * AQT;
    int tid = threadIdx.x;
    int l = tid & 63, w = tid >> 6;
    int ml = l & 15, quad = l >> 4;
    size_t rowbase = (size_t)b * T;

    // Q fragments, held for the whole kernel (A-operand layout)
    bf16x8 qf[2][2];
    #pragma unroll
    for (int mi = 0; mi < 2; ++mi) {
        int qrow = t0 + w * 32 + mi * 16 + ml;
        if (qrow >= T) qrow = T - 1;
        const unsigned short* qp = qb + (rowbase + qrow) * qs + h * HD + quad * 8;
        qf[mi][0] = *(const bf16x8*)qp;
        qf[mi][1] = *(const bf16x8*)(qp + 32);
    }

    f32x4 oacc[2][4] = {};       // [mi][ni], rows quad*4+r, cols d=ni*16+ml
    float mrow[2][4], lrow[2][4];
    #pragma unroll
    for (int mi = 0; mi < 2; ++mi)
        #pragma unroll
        for (int r = 0; r < 4; ++r) { mrow[mi][r] = -1e30f; lrow[mi][r] = 0.f; }

    for (int c0 = 0; c0 < T; c0 += 64) {
        __syncthreads();
        // stage K chunk: Ks[key][72], d contiguous
        #pragma unroll
        for (int it = 0; it < 2; ++it) {
            int c = tid + it * 256;            // 512 x 16B
            int key = c >> 3, cc = c & 7;
            bf16x8 kv = *(const bf16x8*)(kb + (rowbase + c0 + key) * qs + h * HD + cc * 8);
            *(bf16x8*)(Ks + key * 72 + cc * 8) = kv;
        }
        // stage V^T chunk: Vt[d][72], key contiguous
        #pragma unroll
        for (int it = 0; it < 4; ++it) {
            int c = tid + it * 256;            // 1024 x ushort4
            int key = c >> 4, cc = c & 15;
            ushort4 vv = *(const ushort4*)(vb + (rowbase + c0 + key) * qs + h * HD + cc * 4);
            Vt[(cc * 4 + 0) * 72 + key] = vv.x;
            Vt[(cc * 4 + 1) * 72 + key] = vv.y;
            Vt[(cc * 4 + 2) * 72 + key] = vv.z;
            Vt[(cc * 4 + 3) * 72 + key] = vv.w;
        }
        __syncthreads();

        // S = Q K^T
        f32x4 s[2][4] = {};
        #pragma unroll
        for (int ni = 0; ni < 4; ++ni) {
            bf16x8 kf0 = *(const bf16x8*)(Ks + (ni * 16 + ml) * 72 + quad * 8);
            bf16x8 kf1 = *(const bf16x8*)(Ks + (ni * 16 + ml) * 72 + 32 + quad * 8);
            #pragma unroll
            for (int mi = 0; mi < 2; ++mi) {
                s[mi][ni] = __builtin_amdgcn_mfma_f32_16x16x32_bf16(qf[mi][0], kf0, s[mi][ni], 0, 0, 0);
                s[mi][ni] = __builtin_amdgcn_mfma_f32_16x16x32_bf16(qf[mi][1], kf1, s[mi][ni], 0, 0, 0);
            }
        }
        // scale + mask invalid keys
        #pragma unroll
        for (int ni = 0; ni < 4; ++ni) {
            bool valid = (c0 + ni * 16 + ml) < T;
            #pragma unroll
            for (int mi = 0; mi < 2; ++mi)
                #pragma unroll
                for (int r = 0; r < 4; ++r)
                    s[mi][ni][r] = valid ? s[mi][ni][r] * 0.125f : -1e30f;
        }
        // online softmax per row
        #pragma unroll
        for (int mi = 0; mi < 2; ++mi) {
            #pragma unroll
            for (int r = 0; r < 4; ++r) {
                float mx = fmaxf(fmaxf(s[mi][0][r], s[mi][1][r]),
                                 fmaxf(s[mi][2][r], s[mi][3][r]));
                #pragma unroll
                for (int off = 1; off < 16; off <<= 1)
                    mx = fmaxf(mx, __shfl_xor(mx, off));
                float mnew = fmaxf(mrow[mi][r], mx);
                float alpha = __expf(mrow[mi][r] - mnew);
                mrow[mi][r] = mnew;
                float rs = 0.f;
                #pragma unroll
                for (int ni = 0; ni < 4; ++ni) {
                    float p = __expf(s[mi][ni][r] - mnew);
                    s[mi][ni][r] = p; rs += p;
                }
                #pragma unroll
                for (int off = 1; off < 16; off <<= 1)
                    rs += __shfl_xor(rs, off);
                lrow[mi][r] = lrow[mi][r] * alpha + rs;
                #pragma unroll
                for (int ni = 0; ni < 4; ++ni) oacc[mi][ni][r] *= alpha;
            }
        }
        // P -> wave-private LDS (bf16), [q 0..31][key 0..63], stride 72
        unsigned short* pw = Ps[w];
        #pragma unroll
        for (int mi = 0; mi < 2; ++mi)
            #pragma unroll
            for (int r = 0; r < 4; ++r)
                #pragma unroll
                for (int ni = 0; ni < 4; ++ni)
                    pw[(mi * 16 + quad * 4 + r) * 72 + ni * 16 + ml] = f2bf(s[mi][ni][r]);
        // O += P V   (wave-private Ps: no barrier needed)
        #pragma unroll
        for (int kc = 0; kc < 2; ++kc) {
            bf16x8 pf[2];
            pf[0] = *(const bf16x8*)(pw + (ml) * 72 + kc * 32 + quad * 8);
            pf[1] = *(const bf16x8*)(pw + (16 + ml) * 72 + kc * 32 + quad * 8);
            #pragma unroll
            for (int ni = 0; ni < 4; ++ni) {
                bf16x8 vf = *(const bf16x8*)(Vt + (ni * 16 + ml) * 72 + kc * 32 + quad * 8);
                #pragma unroll
                for (int mi = 0; mi < 2; ++mi)
                    oacc[mi][ni] = __builtin_amdgcn_mfma_f32_16x16x32_bf16(pf[mi], vf, oacc[mi][ni], 0, 0, 0);
            }
        }
    }

    // epilogue: O / l, write bf16
    #pragma unroll
    for (int mi = 0; mi < 2; ++mi) {
        #pragma unroll
        for (int r = 0; r < 4; ++r) {
            int grow = t0 + w * 32 + mi * 16 + quad * 4 + r;
            if (grow >= T) continue;
            float inv = 1.f / lrow[mi][r];
            unsigned short* op = ob + (rowbase + grow) * DM + h * HD;
            #pragma unroll
            for (int ni = 0; ni < 4; ++ni)
                op[ni * 16 + ml] = f2bf(oacc[mi][ni][r] * inv);
        }
    }
}

// ---------------------------------------------------------------------------
// Encoder: writes fp32 h and bf16 shadow hb
// ---------------------------------------------------------------------------
__global__ __launch_bounds__(256) void encoder_kernel(
    const float* __restrict__ x, const float* __restrict__ W_enc,
    const float* __restrict__ b_enc, const float* __restrict__ cls_tok,
    const float* __restrict__ pos_emb, float* __restrict__ h,
    unsigned short* __restrict__ hb)
{
    int row = blockIdx.x;
    int b = row / T, tt = row % T;
    int tid = threadIdx.x;
    float* hp = h + (size_t)row * DM;
    unsigned short* hbp = hb + (size_t)row * DM;
    if (tt == 0) {
        float a0 = cls_tok[tid]       + pos_emb[tid];
        float a1 = cls_tok[tid + 256] + pos_emb[tid + 256];
        hp[tid] = a0; hp[tid + 256] = a1;
        hbp[tid] = f2bf(a0); hbp[tid + 256] = f2bf(a1);
        return;
    }
    __shared__ float xs[NTOK];
    int s = tt - 1;
    if (tid < NTOK) xs[tid] = x[((size_t)b * SEQ + s) * NTOK + tid];
    __syncthreads();
    #pragma unroll
    for (int rep = 0; rep < 2; ++rep) {
        int d = tid + rep * 256;
        float acc = b_enc[d] + pos_emb[(size_t)tt * DM + d];
        for (int kx = 0; kx < NTOK; ++kx) acc += xs[kx] * W_enc[kx * DM + d];
        hp[d] = acc;
        hbp[d] = f2bf(acc);
    }
}

// ---------------------------------------------------------------------------
// Fused residual + LayerNorm, wave-per-row (4 rows / 256-thread block):
// h = LN(h + r)*g + be; writes bf16 shadow hb. No barriers, shfl reductions.
// ---------------------------------------------------------------------------
__global__ __launch_bounds__(256) void add_ln_kernel(
    float* __restrict__ h, const float* __restrict__ r,
    const float* __restrict__ g, const float* __restrict__ be,
    unsigned short* __restrict__ hb)
{
    int w = threadIdx.x >> 6, l = threadIdx.x & 63;
    int row = blockIdx.x * 4 + w;
    if (row >= ROWS) return;
    float* hp = h + (size_t)row * DM + l * 8;
    const float* rp = r + (size_t)row * DM + l * 8;
    unsigned short* hbp = hb + (size_t)row * DM + l * 8;
    float4 a0 = *(const float4*)(hp);
    float4 a1 = *(const float4*)(hp + 4);
    float4 b0 = *(const float4*)(rp);
    float4 b1 = *(const float4*)(rp + 4);
    float v[8] = {a0.x + b0.x, a0.y + b0.y, a0.z + b0.z, a0.w + b0.w,
                  a1.x + b1.x, a1.y + b1.y, a1.z + b1.z, a1.w + b1.w};
    float s = 0.f;
    #pragma unroll
    for (int i = 0; i < 8; ++i) s += v[i];
    #pragma unroll
    for (int off = 1; off < 64; off <<= 1) s += __shfl_xor(s, off);
    float mean = s * (1.f / DM);
    float sq = 0.f;
    #pragma unroll
    for (int i = 0; i < 8; ++i) { v[i] -= mean; sq += v[i] * v[i]; }
    #pragma unroll
    for (int off = 1; off < 64; off <<= 1) sq += __shfl_xor(sq, off);
    float inv = rsqrtf(sq * (1.f / DM) + 1e-5f);
    float4 g0 = *(const float4*)(g + l * 8);
    float4 g1 = *(const float4*)(g + l * 8 + 4);
    float4 e0 = *(const float4*)(be + l * 8);
    float4 e1 = *(const float4*)(be + l * 8 + 4);
    float o[8];
    o[0] = v[0]*inv*g0.x + e0.x; o[1] = v[1]*inv*g0.y + e0.y;
    o[2] = v[2]*inv*g0.z + e0.z; o[3] = v[3]*inv*g0.w + e0.w;
    o[4] = v[4]*inv*g1.x + e1.x; o[5] = v[5]*inv*g1.y + e1.y;
    o[6] = v[6]*inv*g1.z + e1.z; o[7] = v[7]*inv*g1.w + e1.w;
    *(float4*)(hp)     = make_float4(o[0], o[1], o[2], o[3]);
    *(float4*)(hp + 4) = make_float4(o[4], o[5], o[6], o[7]);
    ushort4 p0 = {f2bf(o[0]), f2bf(o[1]), f2bf(o[2]), f2bf(o[3])};
    ushort4 p1 = {f2bf(o[4]), f2bf(o[5]), f2bf(o[6]), f2bf(o[7])};
    *(ushort4*)(hbp)     = p0;
    *(ushort4*)(hbp + 4) = p1;
}

// ---------------------------------------------------------------------------
// Decoder stage 1: partial[b][kc][m] = sum_{kx in chunk kc} cls_b[kx]*Wd1[kx][m]
// grid (8, 5), 256 threads.
// ---------------------------------------------------------------------------
__global__ __launch_bounds__(256) void dec1_kernel(
    const float* __restrict__ h, const float* __restrict__ Wd1,
    float* __restrict__ part)
{
    int kc = blockIdx.x, b = blockIdx.y, tid = threadIdx.x;
    __shared__ float cs[64];
    const float* cls = h + (size_t)b * T * DM;
    if (tid < 64) cs[tid] = cls[kc * 64 + tid];
    __syncthreads();
    float acc = 0.f;
    #pragma unroll
    for (int kx = 0; kx < 64; ++kx)
        acc += cs[kx] * Wd1[(size_t)(kc * 64 + kx) * MLPDIM + tid];
    part[(size_t)(b * 8 + kc) * MLPDIM + tid] = acc;
}

// Decoder stage 2: reduce partials + bd1, then @Wd2 + bd2. 1 block.
__global__ __launch_bounds__(256) void dec2_kernel(
    const float* __restrict__ part, const float* __restrict__ bd1,
    const float* __restrict__ Wd2, const float* __restrict__ bd2,
    float* __restrict__ out)
{
    __shared__ float t1s[MLPDIM];
    int tid = threadIdx.x;
    for (int b = 0; b < NBATCH; ++b) {
        float acc = bd1[tid];
        #pragma unroll
        for (int kc = 0; kc < 8; ++kc)
            acc += part[(size_t)(b * 8 + kc) * MLPDIM + tid];
        t1s[tid] = acc;
        __syncthreads();
        if (tid < NCLS) {
            float a2 = bd2[tid];
            for (int kx = 0; kx < MLPDIM; ++kx) a2 += t1s[kx] * Wd2[kx * NCLS + tid];
            out[b * NCLS + tid] = a2;
        }
        __syncthreads();
    }
}

// ---------------------------------------------------------------------------
// GAT (unchanged)
// ---------------------------------------------------------------------------
__global__ __launch_bounds__(64) void gat_kernel(
    const float* __restrict__ x, const int* __restrict__ adj,
    const float* __restrict__ Wg, const float* __restrict__ ag,
    const float* __restrict__ Wgo, const float* __restrict__ ago,
    float* __restrict__ out)
{
    int g = blockIdx.x;
    int s = g / 5, jj = g % 5;
    int tid = threadIdx.x;
    __shared__ float xs[5][3];
    __shared__ int adjs[25];
    __shared__ float hb[GH][5][GHID];
    __shared__ float o1[GH][5][GHID];
    __shared__ float srcb[GH][5], dstb[GH][5];
    __shared__ float attb[GH][5][5];
    __shared__ float h2[5][5], src2[5], dst2[5], att2[5][5], o2[5][5];

    if (tid < 15) { int n = tid / 3, c = tid % 3;
        xs[n][c] = x[(size_t)n * SEQ * NTOK + (size_t)s * NTOK + jj * 3 + c]; }
    if (tid < 25) adjs[tid] = adj[tid];
    __syncthreads();

    #pragma unroll
    for (int hh = 0; hh < GH; ++hh)
        #pragma unroll
        for (int n = 0; n < 5; ++n)
            hb[hh][n][tid] = xs[n][0] * Wg[hh * 192 + tid]
                           + xs[n][1] * Wg[hh * 192 + 64 + tid]
                           + xs[n][2] * Wg[hh * 192 + 128 + tid];
    __syncthreads();

    if (tid < 15) { int hh = tid / 5, n = tid % 5; float a = 0.f;
        for (int f = 0; f < GHID; ++f) a += hb[hh][n][f] * ag[hh * 128 + f];
        srcb[hh][n] = a;
    } else if (tid >= 32 && tid < 47) { int t2 = tid - 32; int hh = t2 / 5, n = t2 % 5; float a = 0.f;
        for (int f = 0; f < GHID; ++f) a += hb[hh][n][f] * ag[hh * 128 + 64 + f];
        dstb[hh][n] = a;
    }
    __syncthreads();

    if (tid < 15) { int hh = tid / 5, i = tid % 5;
        float e[5]; float mx = -1e30f;
        #pragma unroll
        for (int j2 = 0; j2 < 5; ++j2) {
            float ev = srcb[hh][i] + dstb[hh][j2];
            ev = ev > 0.f ? ev : 0.2f * ev;
            e[j2] = ev;
            if (adjs[i * 5 + j2] && ev > mx) mx = ev;
        }
        float sum = 0.f;
        #pragma unroll
        for (int j2 = 0; j2 < 5; ++j2) {
            float p = adjs[i * 5 + j2] ? expf(e[j2] - mx) : 0.f;
            e[j2] = p; sum += p;
        }
        float inv = 1.f / sum;
        #pragma unroll
        for (int j2 = 0; j2 < 5; ++j2) attb[hh][i][j2] = e[j2] * inv;
    }
    __syncthreads();

    #pragma unroll
    for (int hh = 0; hh < GH; ++hh)
        #pragma unroll
        for (int n = 0; n < 5; ++n) {
            float a = 0.f;
            #pragma unroll
            for (int j2 = 0; j2 < 5; ++j2) a += attb[hh][n][j2] * hb[hh][j2][tid];
            o1[hh][n][tid] = a > 0.f ? a : expm1f(a);
        }
    __syncthreads();

    if (tid < 25) { int n = tid / 5, m = tid % 5; float a = 0.f;
        for (int hh = 0; hh < GH; ++hh)
            for (int f = 0; f < GHID; ++f)
                a += o1[hh][n][f] * Wgo[(hh * GHID + f) * GCLS + m];
        h2[n][m] = a;
    }
    __syncthreads();

    if (tid < 5) { float a = 0.f;
        for (int m = 0; m < GCLS; ++m) a += h2[tid][m] * ago[m];
        src2[tid] = a;
    } else if (tid >= 8 && tid < 13) { int n = tid - 8; float a = 0.f;
        for (int m = 0; m < GCLS; ++m) a += h2[n][m] * ago[GCLS + m];
        dst2[n] = a;
    }
    __syncthreads();

    if (tid < 5) { int i = tid;
        float e[5]; float mx = -1e30f;
        #pragma unroll
        for (int j2 = 0; j2 < 5; ++j2) {
            float ev = src2[i] + dst2[j2];
            ev = ev > 0.f ? ev : 0.2f * ev;
            e[j2] = ev;
            if (adjs[i * 5 + j2] && ev > mx) mx = ev;
        }
        float sum = 0.f;
        #pragma unroll
        for (int j2 = 0; j2 < 5; ++j2) {
            float p = adjs[i * 5 + j2] ? expf(e[j2] - mx) : 0.f;
            e[j2] = p; sum += p;
        }
        float inv = 1.f / sum;
        #pragma unroll
        for (int j2 = 0; j2 < 5; ++j2) att2[i][j2] = e[j2] * inv;
    }
    __syncthreads();

    if (tid < 25) { int n = tid / 5, m = tid % 5; float a = 0.f;
        #pragma unroll
        for (int j2 = 0; j2 < 5; ++j2) a += att2[n][j2] * h2[j2][m];
        o2[n][m] = a > 0.f ? a : expm1f(a);
    }
    __syncthreads();

    if (tid < 5) { int n = tid;
        float mx = o2[n][0];
        #pragma unroll
        for (int m = 1; m < GCLS; ++m) mx = fmaxf(mx, o2[n][m]);
        float sum = 0.f;
        #pragma unroll
        for (int m = 0; m < GCLS; ++m) sum += expf(o2[n][m] - mx);
        float ls = logf(sum);
        #pragma unroll
        for (int m = 0; m < GCLS; ++m)
            out[(size_t)g * 25 + n * 5 + m] = o2[n][m] - mx - ls;
    }
}

// ---------------------------------------------------------------------------
// Launch
// ---------------------------------------------------------------------------
extern "C" void kernel_launch(void* const* d_in, const int* in_sizes, int n_in,
                              void* d_out, int out_size, void* d_ws, size_t ws_size,
                              hipStream_t stream)
{
    const float* x       = (const float*)d_in[0];
    const int*   adj     = (const int*)  d_in[1];
    const float* W_enc   = (const float*)d_in[2];
    const float* b_enc   = (const float*)d_in[3];
    const float* cls_tok = (const float*)d_in[4];
    const float* pos_emb = (const float*)d_in[5];
    const float* Wq = (const float*)d_in[6];
    const float* bq = (const float*)d_in[7];
    const float* Wk = (const float*)d_in[8];
    const float* bk = (const float*)d_in[9];
    const float* Wv = (const float*)d_in[10];
    const float* bv = (const float*)d_in[11];
    const float* Wo = (const float*)d_in[12];
    const float* bo = (const float*)d_in[13];
    const float* W1 = (const float*)d_in[14];
    const float* b1 = (const float*)d_in[15];
    const float* W2 = (const float*)d_in[16];
    const float* b2 = (const float*)d_in[17];
    const float* g1 = (const float*)d_in[18];
    const float* be1= (const float*)d_in[19];
    const float* g2 = (const float*)d_in[20];
    const float* be2= (const float*)d_in[21];
    const float* Wd1= (const float*)d_in[22];
    const float* bd1= (const float*)d_in[23];
    const float* Wd2= (const float*)d_in[24];
    const float* bd2= (const float*)d_in[25];
    const float* Wg = (const float*)d_in[26];
    const float* ag = (const float*)d_in[27];
    const float* Wgo= (const float*)d_in[28];
    const float* ago= (const float*)d_in[29];
    float* out = (float*)d_out;

    // workspace layout:
    //   h, q : fp32 [MP][512]; hb : bf16 [MP][512]
    //   qkvb bf16 [MP][1536] + ob bf16 [MP][512]; f1b bf16 [MP][2048] aliases both
    //   Wqkvt bf16 [4][1536][512] (Wq/Wk/Wv interleaved per layer)
    //   Wot [4][512][512], W1t [4][2048][512], W2t [4][512][2048]
    //   bqkv fp32 [4][1536], dpart fp32 [5][8][256]
    float* ws = (float*)d_ws;
    float* h = ws;
    float* q = h + (size_t)MP * DM;
    unsigned short* hb   = (unsigned short*)(q + (size_t)MP * DM);
    unsigned short* qkvb = hb + (size_t)MP * DM;
    unsigned short* ob   = qkvb + (size_t)MP * QKVN;
    unsigned short* f1b  = qkvb;                    // alias qkvb+ob
    unsigned short* Wqkvt= ob + (size_t)MP * DM;
    unsigned short* Wot  = Wqkvt + (size_t)4 * QKVN * DM;
    unsigned short* W1t  = Wot + (size_t)4 * DM * DM;
    unsigned short* W2t  = W1t + (size_t)4 * DM * DFF;
    float* bqkv = (float*)(W2t + (size_t)4 * DFF * DM);
    float* dpart = bqkv + 4 * QKVN;

    const long QS = (long)QKVN * DM;   // per-layer stride in Wqkvt
    wconv_kernel<<<dim3(DM/32,  DM/32,  4), 256, 0, stream>>>(Wq, Wqkvt,            DM,  DM, QS);
    wconv_kernel<<<dim3(DM/32,  DM/32,  4), 256, 0, stream>>>(Wk, Wqkvt + 512*512,  DM,  DM, QS);
    wconv_kernel<<<dim3(DM/32,  DM/32,  4), 256, 0, stream>>>(Wv, Wqkvt + 1024*512, DM,  DM, QS);
    wconv_kernel<<<dim3(DM/32,  DM/32,  4), 256, 0, stream>>>(Wo, Wot, DM,  DM, (long)DM*DM);
    wconv_kernel<<<dim3(DFF/32, DM/32,  4), 256, 0, stream>>>(W1, W1t, DM,  DFF, (long)DM*DFF);
    wconv_kernel<<<dim3(DM/32,  DFF/32, 4), 256, 0, stream>>>(W2, W2t, DFF, DM, (long)DFF*DM);
    bconcat_kernel<<<4, 512, 0, stream>>>(bq, bk, bv, bqkv);

    gat_kernel<<<NGRAPH, 64, 0, stream>>>(x, adj, Wg, ag, Wgo, ago, out + NBATCH * NCLS);
    encoder_kernel<<<ROWS, 256, 0, stream>>>(x, W_enc, b_enc, cls_tok, pos_emb, h, hb);

    dim3 g512 (DM  / 128, MP / 128);   // (4, 41)
    dim3 gqkv (QKVN / 128, MP / 128);  // (12, 41)
    dim3 g2048(DFF / 128, MP / 128);   // (16, 41)
    dim3 gAttn((T + AQT - 1) / AQT, NBATCH * NHEAD);  // (9, 40)
    int gLN = (ROWS + 3) / 4;

    for (int i = 0; i < 4; ++i) {
        gemm_mfma<<<gqkv, 256, 0, stream>>>(hb, Wqkvt + (size_t)i*QKVN*DM, bqkv + i*QKVN, nullptr, qkvb, QKVN, DM, 0);
        attn_mfma<<<gAttn, 256, 0, stream>>>(qkvb, qkvb + 512, qkvb + 1024, ob, QKVN);
        gemm_mfma<<<g512, 256, 0, stream>>>(ob, Wot + (size_t)i*DM*DM, bo + i*DM, q, nullptr, DM, DM, 0);
        add_ln_kernel<<<gLN, 256, 0, stream>>>(h, q, g1 + i*DM, be1 + i*DM, hb);
        gemm_mfma<<<g2048, 256, 0, stream>>>(hb,  W1t + (size_t)i*DM*DFF, b1 + i*DFF, nullptr, f1b, DFF, DM, 1);
        gemm_mfma<<<g512, 256, 0, stream>>>(f1b, W2t + (size_t)i*DM*DFF, b2 + i*DM,  q, nullptr, DM, DFF, 0);
        add_ln_kernel<<<gLN, 256, 0, stream>>>(h, q, g2 + i*DM, be2 + i*DM, hb);
    }

    dec1_kernel<<<dim3(8, NBATCH), 256, 0, stream>>>(h, Wd1, dpart);
    dec2_kernel<<<1, 256, 0, stream>>>(dpart, bd1, Wd2, bd2, out);
}

// Round 6
// 959.072 us; speedup vs baseline: 14.6079x; 1.0830x over previous
//
#include <hip/hip_runtime.h>
#include <hip/hip_bf16.h>
#include <math.h>

// ---------------------------------------------------------------------------
// Model constants
// ---------------------------------------------------------------------------
#define NBATCH 5
#define SEQ    1024
#define T      1025          // SEQ + 1 (cls token)
#define ROWS   (NBATCH * T)  // 5125
#define MP     5248          // ROWS padded to 41*128 for MFMA tiles
#define DM     512
#define DFF    2048
#define NHEAD  8
#define HD     64
#define NTOK   51
#define MLPDIM 256
#define NCLS   7
#define GH     3
#define GHID   64
#define GCLS   5
#define NGRAPH (SEQ * 5)     // 5120
#define QKVN   1536          // fused QKV output width
#define TPAD   1088          // T padded to 17*64 for V^T buffer

typedef __attribute__((ext_vector_type(8))) short bf16x8;
typedef __attribute__((ext_vector_type(4))) float f32x4;

#define GM_AS(p)  ((const __attribute__((address_space(1))) void*)(p))
#define LDS_AS(p) ((__attribute__((address_space(3))) void*)(p))

__device__ __forceinline__ unsigned short f2bf(float f) {
    unsigned int u = __float_as_uint(f);
    unsigned int r = (u + 0x7FFFu + ((u >> 16) & 1u)) >> 16;
    return (unsigned short)r;
}

// ---------------------------------------------------------------------------
// Weight transpose + fp32->bf16: W[K][N] (mat z at z*K*N) -> Wt (at z*dstride),
// layout [N][K]. dstride lets us interleave Wq/Wk/Wv per layer.
// ---------------------------------------------------------------------------
__global__ __launch_bounds__(256) void wconv_kernel(
    const float* __restrict__ W, unsigned short* __restrict__ Wt, int K, int N,
    long dstride)
{
    const float* Wm = W + (size_t)blockIdx.z * K * N;
    unsigned short* Wo = Wt + (size_t)blockIdx.z * dstride;
    __shared__ float tile[32][33];
    int bx = blockIdx.x * 32;   // N dir
    int by = blockIdx.y * 32;   // K dir
    int tx = threadIdx.x & 31, ty = threadIdx.x >> 5;   // 32 x 8
    #pragma unroll
    for (int i = 0; i < 32; i += 8)
        tile[ty + i][tx] = Wm[(size_t)(by + ty + i) * N + bx + tx];
    __syncthreads();
    #pragma unroll
    for (int i = 0; i < 32; i += 8)
        Wo[(size_t)(bx + ty + i) * K + by + tx] = f2bf(tile[tx][ty + i]);
}

// Concat per-layer biases bq|bk|bv -> bqkv[L][1536]
__global__ __launch_bounds__(512) void bconcat_kernel(
    const float* __restrict__ bq, const float* __restrict__ bk,
    const float* __restrict__ bv, float* __restrict__ bqkv)
{
    int i = blockIdx.x, t = threadIdx.x;
    bqkv[i * QKVN + t]        = bq[i * DM + t];
    bqkv[i * QKVN + 512 + t]  = bk[i * DM + t];
    bqkv[i * QKVN + 1024 + t] = bv[i * DM + t];
}

// ---------------------------------------------------------------------------
// bf16 MFMA GEMM (m97 structure): C[M][N] = A[M][K] @ Bt[N][K]^T + bias.
// 128x128 block tile, BK=32, 256 threads = 4 waves in 2x2, each wave 64x64.
// ---------------------------------------------------------------------------
__global__ __launch_bounds__(256) void gemm_mfma(
    const unsigned short* __restrict__ A, const unsigned short* __restrict__ Bt,
    const float* __restrict__ bias, float* __restrict__ Cf,
    unsigned short* __restrict__ Cb, int N, int K, int relu)
{
    __shared__ unsigned short As[128 * 32];
    __shared__ unsigned short Bs[128 * 32];
    int tid = threadIdx.x;
    int l = tid & 63, w = tid >> 6;
    int wr = w & 1, wc = w >> 1;
    int mlane = l & 15, quad = l >> 4;
    int m0 = blockIdx.y * 128, n0 = blockIdx.x * 128;

    f32x4 acc[4][4] = {};   // [mi][ni]

    for (int k0 = 0; k0 < K; k0 += 32) {
        __syncthreads();
        #pragma unroll
        for (int it = 0; it < 2; ++it) {
            int c = tid + it * 256;          // 16B chunk id, 4 chunks/row
            int row = c >> 2, cc = c & 3;
            const unsigned short* ga = A  + (size_t)(m0 + row) * K + k0 + cc * 8;
            __builtin_amdgcn_global_load_lds(GM_AS(ga), LDS_AS(As + c * 8), 16, 0, 0);
            const unsigned short* gb = Bt + (size_t)(n0 + row) * K + k0 + cc * 8;
            __builtin_amdgcn_global_load_lds(GM_AS(gb), LDS_AS(Bs + c * 8), 16, 0, 0);
        }
        __syncthreads();
        bf16x8 afrag[4], bfrag[4];
        #pragma unroll
        for (int mi = 0; mi < 4; ++mi)
            afrag[mi] = *(const bf16x8*)(As + (wr * 64 + mi * 16 + mlane) * 32 + quad * 8);
        #pragma unroll
        for (int ni = 0; ni < 4; ++ni)
            bfrag[ni] = *(const bf16x8*)(Bs + (wc * 64 + ni * 16 + mlane) * 32 + quad * 8);
        #pragma unroll
        for (int mi = 0; mi < 4; ++mi)
            #pragma unroll
            for (int ni = 0; ni < 4; ++ni)
                acc[mi][ni] = __builtin_amdgcn_mfma_f32_16x16x32_bf16(
                    afrag[mi], bfrag[ni], acc[mi][ni], 0, 0, 0);
    }

    // C/D layout: col = lane&15, row = quad*4 + reg
    #pragma unroll
    for (int mi = 0; mi < 4; ++mi) {
        #pragma unroll
        for (int r = 0; r < 4; ++r) {
            int gm = m0 + wr * 64 + mi * 16 + quad * 4 + r;
            size_t rowoff = (size_t)gm * N;
            #pragma unroll
            for (int ni = 0; ni < 4; ++ni) {
                int gn = n0 + wc * 64 + ni * 16 + mlane;
                float val = acc[mi][ni][r] + bias[gn];
                if (relu) val = fmaxf(val, 0.f);
                if (Cb) Cb[rowoff + gn] = f2bf(val);
                else    Cf[rowoff + gn] = val;
            }
        }
    }
}

// ---------------------------------------------------------------------------
// V transpose per layer: vb rows (b,t) stride qs, cols h*64+d  ->
// vt[(bh*64 + d)][TPAD] (key-major rows). One 64-key tile per block.
// ---------------------------------------------------------------------------
__global__ __launch_bounds__(256) void vtrans_kernel(
    const unsigned short* __restrict__ vb, unsigned short* __restrict__ vt, int qs)
{
    __shared__ unsigned short tile[64][72];
    int bh = blockIdx.y;
    int b = bh >> 3, h = bh & 7;
    int t0 = blockIdx.x * 64;
    int tid = threadIdx.x;
    #pragma unroll
    for (int it = 0; it < 2; ++it) {
        int c = tid + it * 256;
        int key = c >> 3, cc = c & 7;
        int gk = t0 + key; if (gk >= T) gk = T - 1;
        *(bf16x8*)(&tile[key][cc * 8]) =
            *(const bf16x8*)(vb + ((size_t)b * T + gk) * qs + h * HD + cc * 8);
    }
    __syncthreads();
    #pragma unroll
    for (int it = 0; it < 2; ++it) {
        int c = tid + it * 256;
        int d = c >> 3, cc = c & 7;
        unsigned short tmp[8];
        #pragma unroll
        for (int j = 0; j < 8; ++j) tmp[j] = tile[cc * 8 + j][d];
        *(bf16x8*)(vt + ((size_t)bh * 64 + d) * TPAD + t0 + cc * 8) = *(bf16x8*)tmp;
    }
}

// ---------------------------------------------------------------------------
// bf16 MFMA flash attention. Block = 64 queries x (b,h); 4 waves, each 16 q.
// K staged [key][72] b128; V^T staged from pre-transposed global (b128, no
// scalar transpose). P round-trips wave-private LDS with XOR-swizzled columns
// (col' = col ^ ((q>>2&3)<<4)) -> all-bank 2-way writes, aligned b128 reads.
// ---------------------------------------------------------------------------
#define AQT 64
__global__ __launch_bounds__(256) void attn_mfma(
    const unsigned short* __restrict__ qb, const unsigned short* __restrict__ kb,
    const unsigned short* __restrict__ vt, unsigned short* __restrict__ ob,
    int qs)
{
    __shared__ unsigned short Ks[64 * 72];
    __shared__ unsigned short Vs[64 * 72];
    __shared__ unsigned short Ps[4][16 * 72];
    int bh = blockIdx.y;
    int b = bh >> 3, h = bh & 7;
    int t0 = blockIdx.x * AQT;
    int tid = threadIdx.x;
    int l = tid & 63, w = tid >> 6;
    int ml = l & 15, quad = l >> 4;
    size_t rowbase = (size_t)b * T;
    const unsigned short* vtb = vt + (size_t)bh * 64 * TPAD;

    int qrow = t0 + w * 16 + ml; if (qrow >= T) qrow = T - 1;
    const unsigned short* qp = qb + (rowbase + qrow) * qs + h * HD + quad * 8;
    bf16x8 qf0 = *(const bf16x8*)qp;
    bf16x8 qf1 = *(const bf16x8*)(qp + 32);

    f32x4 oacc[4] = {};
    float mrow[4] = {-1e30f, -1e30f, -1e30f, -1e30f};
    float lrow[4] = {0.f, 0.f, 0.f, 0.f};

    for (int c0 = 0; c0 < T; c0 += 64) {
        __syncthreads();
        #pragma unroll
        for (int it = 0; it < 2; ++it) {
            int c = tid + it * 256;
            int row = c >> 3, cc = c & 7;   // row = key (Ks) / d (Vs)
            int gk = c0 + row; if (gk >= T) gk = T - 1;
            *(bf16x8*)(Ks + row * 72 + cc * 8) =
                *(const bf16x8*)(kb + (rowbase + gk) * qs + h * HD + cc * 8);
            *(bf16x8*)(Vs + row * 72 + cc * 8) =
                *(const bf16x8*)(vtb + (size_t)row * TPAD + c0 + cc * 8);
        }
        __syncthreads();

        // S = Q K^T
        f32x4 s[4] = {};
        #pragma unroll
        for (int ni = 0; ni < 4; ++ni) {
            bf16x8 kf0 = *(const bf16x8*)(Ks + (ni * 16 + ml) * 72 + quad * 8);
            bf16x8 kf1 = *(const bf16x8*)(Ks + (ni * 16 + ml) * 72 + 32 + quad * 8);
            s[ni] = __builtin_amdgcn_mfma_f32_16x16x32_bf16(qf0, kf0, s[ni], 0, 0, 0);
            s[ni] = __builtin_amdgcn_mfma_f32_16x16x32_bf16(qf1, kf1, s[ni], 0, 0, 0);
        }
        // scale + mask invalid keys
        #pragma unroll
        for (int ni = 0; ni < 4; ++ni) {
            bool valid = (c0 + ni * 16 + ml) < T;
            #pragma unroll
            for (int r = 0; r < 4; ++r)
                s[ni][r] = valid ? s[ni][r] * 0.125f : -1e30f;
        }
        // online softmax per row (row = quad*4+r; reduce over 16 ml lanes)
        #pragma unroll
        for (int r = 0; r < 4; ++r) {
            float mx = fmaxf(fmaxf(s[0][r], s[1][r]), fmaxf(s[2][r], s[3][r]));
            #pragma unroll
            for (int off = 1; off < 16; off <<= 1)
                mx = fmaxf(mx, __shfl_xor(mx, off));
            float mnew = fmaxf(mrow[r], mx);
            float alpha = __expf(mrow[r] - mnew);
            mrow[r] = mnew;
            float rs = 0.f;
            #pragma unroll
            for (int ni = 0; ni < 4; ++ni) {
                float p = __expf(s[ni][r] - mnew);
                s[ni][r] = p; rs += p;
            }
            #pragma unroll
            for (int off = 1; off < 16; off <<= 1)
                rs += __shfl_xor(rs, off);
            lrow[r] = lrow[r] * alpha + rs;
            #pragma unroll
            for (int ni = 0; ni < 4; ++ni) oacc[ni][r] *= alpha;
        }
        // P -> wave-private LDS with XOR swizzle (write conflicts ~2-way)
        unsigned short* pw = Ps[w];
        #pragma unroll
        for (int r = 0; r < 4; ++r)
            #pragma unroll
            for (int ni = 0; ni < 4; ++ni)
                pw[(quad * 4 + r) * 72 + ((ni * 16 + ml) ^ (quad << 4))] = f2bf(s[ni][r]);
        // O += P V (wave-private Ps; same-wave DS ordering, no barrier)
        int sw = ((ml >> 2) & 3) << 4;
        #pragma unroll
        for (int kc = 0; kc < 2; ++kc) {
            bf16x8 pf = *(const bf16x8*)(pw + ml * 72 + ((kc * 32 + quad * 8) ^ sw));
            #pragma unroll
            for (int ni = 0; ni < 4; ++ni) {
                bf16x8 vf = *(const bf16x8*)(Vs + (ni * 16 + ml) * 72 + kc * 32 + quad * 8);
                oacc[ni] = __builtin_amdgcn_mfma_f32_16x16x32_bf16(pf, vf, oacc[ni], 0, 0, 0);
            }
        }
    }

    // epilogue: O / l, write bf16
    #pragma unroll
    for (int r = 0; r < 4; ++r) {
        int grow = t0 + w * 16 + quad * 4 + r;
        if (grow >= T) continue;
        float inv = 1.f / lrow[r];
        unsigned short* op = ob + (rowbase + grow) * DM + h * HD;
        #pragma unroll
        for (int ni = 0; ni < 4; ++ni)
            op[ni * 16 + ml] = f2bf(oacc[ni][r] * inv);
    }
}

// ---------------------------------------------------------------------------
// Encoder: writes fp32 h and bf16 shadow hb
// ---------------------------------------------------------------------------
__global__ __launch_bounds__(256) void encoder_kernel(
    const float* __restrict__ x, const float* __restrict__ W_enc,
    const float* __restrict__ b_enc, const float* __restrict__ cls_tok,
    const float* __restrict__ pos_emb, float* __restrict__ h,
    unsigned short* __restrict__ hb)
{
    int row = blockIdx.x;
    int b = row / T, tt = row % T;
    int tid = threadIdx.x;
    float* hp = h + (size_t)row * DM;
    unsigned short* hbp = hb + (size_t)row * DM;
    if (tt == 0) {
        float a0 = cls_tok[tid]       + pos_emb[tid];
        float a1 = cls_tok[tid + 256] + pos_emb[tid + 256];
        hp[tid] = a0; hp[tid + 256] = a1;
        hbp[tid] = f2bf(a0); hbp[tid + 256] = f2bf(a1);
        return;
    }
    __shared__ float xs[NTOK];
    int s = tt - 1;
    if (tid < NTOK) xs[tid] = x[((size_t)b * SEQ + s) * NTOK + tid];
    __syncthreads();
    #pragma unroll
    for (int rep = 0; rep < 2; ++rep) {
        int d = tid + rep * 256;
        float acc = b_enc[d] + pos_emb[(size_t)tt * DM + d];
        for (int kx = 0; kx < NTOK; ++kx) acc += xs[kx] * W_enc[kx * DM + d];
        hp[d] = acc;
        hbp[d] = f2bf(acc);
    }
}

// ---------------------------------------------------------------------------
// Fused residual + LayerNorm, wave-per-row (4 rows / 256-thread block)
// ---------------------------------------------------------------------------
__global__ __launch_bounds__(256) void add_ln_kernel(
    float* __restrict__ h, const float* __restrict__ r,
    const float* __restrict__ g, const float* __restrict__ be,
    unsigned short* __restrict__ hb)
{
    int w = threadIdx.x >> 6, l = threadIdx.x & 63;
    int row = blockIdx.x * 4 + w;
    if (row >= ROWS) return;
    float* hp = h + (size_t)row * DM + l * 8;
    const float* rp = r + (size_t)row * DM + l * 8;
    unsigned short* hbp = hb + (size_t)row * DM + l * 8;
    float4 a0 = *(const float4*)(hp);
    float4 a1 = *(const float4*)(hp + 4);
    float4 b0 = *(const float4*)(rp);
    float4 b1 = *(const float4*)(rp + 4);
    float v[8] = {a0.x + b0.x, a0.y + b0.y, a0.z + b0.z, a0.w + b0.w,
                  a1.x + b1.x, a1.y + b1.y, a1.z + b1.z, a1.w + b1.w};
    float s = 0.f;
    #pragma unroll
    for (int i = 0; i < 8; ++i) s += v[i];
    #pragma unroll
    for (int off = 1; off < 64; off <<= 1) s += __shfl_xor(s, off);
    float mean = s * (1.f / DM);
    float sq = 0.f;
    #pragma unroll
    for (int i = 0; i < 8; ++i) { v[i] -= mean; sq += v[i] * v[i]; }
    #pragma unroll
    for (int off = 1; off < 64; off <<= 1) sq += __shfl_xor(sq, off);
    float inv = rsqrtf(sq * (1.f / DM) + 1e-5f);
    float4 g0 = *(const float4*)(g + l * 8);
    float4 g1 = *(const float4*)(g + l * 8 + 4);
    float4 e0 = *(const float4*)(be + l * 8);
    float4 e1 = *(const float4*)(be + l * 8 + 4);
    float o[8];
    o[0] = v[0]*inv*g0.x + e0.x; o[1] = v[1]*inv*g0.y + e0.y;
    o[2] = v[2]*inv*g0.z + e0.z; o[3] = v[3]*inv*g0.w + e0.w;
    o[4] = v[4]*inv*g1.x + e1.x; o[5] = v[5]*inv*g1.y + e1.y;
    o[6] = v[6]*inv*g1.z + e1.z; o[7] = v[7]*inv*g1.w + e1.w;
    *(float4*)(hp)     = make_float4(o[0], o[1], o[2], o[3]);
    *(float4*)(hp + 4) = make_float4(o[4], o[5], o[6], o[7]);
    ushort4 p0 = {f2bf(o[0]), f2bf(o[1]), f2bf(o[2]), f2bf(o[3])};
    ushort4 p1 = {f2bf(o[4]), f2bf(o[5]), f2bf(o[6]), f2bf(o[7])};
    *(ushort4*)(hbp)     = p0;
    *(ushort4*)(hbp + 4) = p1;
}

// ---------------------------------------------------------------------------
// Decoder stage 1 + stage 2
// ---------------------------------------------------------------------------
__global__ __launch_bounds__(256) void dec1_kernel(
    const float* __restrict__ h, const float* __restrict__ Wd1,
    float* __restrict__ part)
{
    int kc = blockIdx.x, b = blockIdx.y, tid = threadIdx.x;
    __shared__ float cs[64];
    const float* cls = h + (size_t)b * T * DM;
    if (tid < 64) cs[tid] = cls[kc * 64 + tid];
    __syncthreads();
    float acc = 0.f;
    #pragma unroll
    for (int kx = 0; kx < 64; ++kx)
        acc += cs[kx] * Wd1[(size_t)(kc * 64 + kx) * MLPDIM + tid];
    part[(size_t)(b * 8 + kc) * MLPDIM + tid] = acc;
}

__global__ __launch_bounds__(256) void dec2_kernel(
    const float* __restrict__ part, const float* __restrict__ bd1,
    const float* __restrict__ Wd2, const float* __restrict__ bd2,
    float* __restrict__ out)
{
    __shared__ float t1s[MLPDIM];
    int tid = threadIdx.x;
    for (int b = 0; b < NBATCH; ++b) {
        float acc = bd1[tid];
        #pragma unroll
        for (int kc = 0; kc < 8; ++kc)
            acc += part[(size_t)(b * 8 + kc) * MLPDIM + tid];
        t1s[tid] = acc;
        __syncthreads();
        if (tid < NCLS) {
            float a2 = bd2[tid];
            for (int kx = 0; kx < MLPDIM; ++kx) a2 += t1s[kx] * Wd2[kx * NCLS + tid];
            out[b * NCLS + tid] = a2;
        }
        __syncthreads();
    }
}

// ---------------------------------------------------------------------------
// GAT (unchanged)
// ---------------------------------------------------------------------------
__global__ __launch_bounds__(64) void gat_kernel(
    const float* __restrict__ x, const int* __restrict__ adj,
    const float* __restrict__ Wg, const float* __restrict__ ag,
    const float* __restrict__ Wgo, const float* __restrict__ ago,
    float* __restrict__ out)
{
    int g = blockIdx.x;
    int s = g / 5, jj = g % 5;
    int tid = threadIdx.x;
    __shared__ float xs[5][3];
    __shared__ int adjs[25];
    __shared__ float hb[GH][5][GHID];
    __shared__ float o1[GH][5][GHID];
    __shared__ float srcb[GH][5], dstb[GH][5];
    __shared__ float attb[GH][5][5];
    __shared__ float h2[5][5], src2[5], dst2[5], att2[5][5], o2[5][5];

    if (tid < 15) { int n = tid / 3, c = tid % 3;
        xs[n][c] = x[(size_t)n * SEQ * NTOK + (size_t)s * NTOK + jj * 3 + c]; }
    if (tid < 25) adjs[tid] = adj[tid];
    __syncthreads();

    #pragma unroll
    for (int hh = 0; hh < GH; ++hh)
        #pragma unroll
        for (int n = 0; n < 5; ++n)
            hb[hh][n][tid] = xs[n][0] * Wg[hh * 192 + tid]
                           + xs[n][1] * Wg[hh * 192 + 64 + tid]
                           + xs[n][2] * Wg[hh * 192 + 128 + tid];
    __syncthreads();

    if (tid < 15) { int hh = tid / 5, n = tid % 5; float a = 0.f;
        for (int f = 0; f < GHID; ++f) a += hb[hh][n][f] * ag[hh * 128 + f];
        srcb[hh][n] = a;
    } else if (tid >= 32 && tid < 47) { int t2 = tid - 32; int hh = t2 / 5, n = t2 % 5; float a = 0.f;
        for (int f = 0; f < GHID; ++f) a += hb[hh][n][f] * ag[hh * 128 + 64 + f];
        dstb[hh][n] = a;
    }
    __syncthreads();

    if (tid < 15) { int hh = tid / 5, i = tid % 5;
        float e[5]; float mx = -1e30f;
        #pragma unroll
        for (int j2 = 0; j2 < 5; ++j2) {
            float ev = srcb[hh][i] + dstb[hh][j2];
            ev = ev > 0.f ? ev : 0.2f * ev;
            e[j2] = ev;
            if (adjs[i * 5 + j2] && ev > mx) mx = ev;
        }
        float sum = 0.f;
        #pragma unroll
        for (int j2 = 0; j2 < 5; ++j2) {
            float p = adjs[i * 5 + j2] ? expf(e[j2] - mx) : 0.f;
            e[j2] = p; sum += p;
        }
        float inv = 1.f / sum;
        #pragma unroll
        for (int j2 = 0; j2 < 5; ++j2) attb[hh][i][j2] = e[j2] * inv;
    }
    __syncthreads();

    #pragma unroll
    for (int hh = 0; hh < GH; ++hh)
        #pragma unroll
        for (int n = 0; n < 5; ++n) {
            float a = 0.f;
            #pragma unroll
            for (int j2 = 0; j2 < 5; ++j2) a += attb[hh][n][j2] * hb[hh][j2][tid];
            o1[hh][n][tid] = a > 0.f ? a : expm1f(a);
        }
    __syncthreads();

    if (tid < 25) { int n = tid / 5, m = tid % 5; float a = 0.f;
        for (int hh = 0; hh < GH; ++hh)
            for (int f = 0; f < GHID; ++f)
                a += o1[hh][n][f] * Wgo[(hh * GHID + f) * GCLS + m];
        h2[n][m] = a;
    }
    __syncthreads();

    if (tid < 5) { float a = 0.f;
        for (int m = 0; m < GCLS; ++m) a += h2[tid][m] * ago[m];
        src2[tid] = a;
    } else if (tid >= 8 && tid < 13) { int n = tid - 8; float a = 0.f;
        for (int m = 0; m < GCLS; ++m) a += h2[n][m] * ago[GCLS + m];
        dst2[n] = a;
    }
    __syncthreads();

    if (tid < 5) { int i = tid;
        float e[5]; float mx = -1e30f;
        #pragma unroll
        for (int j2 = 0; j2 < 5; ++j2) {
            float ev = src2[i] + dst2[j2];
            ev = ev > 0.f ? ev : 0.2f * ev;
            e[j2] = ev;
            if (adjs[i * 5 + j2] && ev > mx) mx = ev;
        }
        float sum = 0.f;
        #pragma unroll
        for (int j2 = 0; j2 < 5; ++j2) {
            float p = adjs[i * 5 + j2] ? expf(e[j2] - mx) : 0.f;
            e[j2] = p; sum += p;
        }
        float inv = 1.f / sum;
        #pragma unroll
        for (int j2 = 0; j2 < 5; ++j2) att2[i][j2] = e[j2] * inv;
    }
    __syncthreads();

    if (tid < 25) { int n = tid / 5, m = tid % 5; float a = 0.f;
        #pragma unroll
        for (int j2 = 0; j2 < 5; ++j2) a += att2[n][j2] * h2[j2][m];
        o2[n][m] = a > 0.f ? a : expm1f(a);
    }
    __syncthreads();

    if (tid < 5) { int n = tid;
        float mx = o2[n][0];
        #pragma unroll
        for (int m = 1; m < GCLS; ++m) mx = fmaxf(mx, o2[n][m]);
        float sum = 0.f;
        #pragma unroll
        for (int m = 0; m < GCLS; ++m) sum += expf(o2[n][m] - mx);
        float ls = logf(sum);
        #pragma unroll
        for (int m = 0; m < GCLS; ++m)
            out[(size_t)g * 25 + n * 5 + m] = o2[n][m] - mx - ls;
    }
}

// ---------------------------------------------------------------------------
// Launch
// ---------------------------------------------------------------------------
extern "C" void kernel_launch(void* const* d_in, const int* in_sizes, int n_in,
                              void* d_out, int out_size, void* d_ws, size_t ws_size,
                              hipStream_t stream)
{
    const float* x       = (const float*)d_in[0];
    const int*   adj     = (const int*)  d_in[1];
    const float* W_enc   = (const float*)d_in[2];
    const float* b_enc   = (const float*)d_in[3];
    const float* cls_tok = (const float*)d_in[4];
    const float* pos_emb = (const float*)d_in[5];
    const float* Wq = (const float*)d_in[6];
    const float* bq = (const float*)d_in[7];
    const float* Wk = (const float*)d_in[8];
    const float* bk = (const float*)d_in[9];
    const float* Wv = (const float*)d_in[10];
    const float* bv = (const float*)d_in[11];
    const float* Wo = (const float*)d_in[12];
    const float* bo = (const float*)d_in[13];
    const float* W1 = (const float*)d_in[14];
    const float* b1 = (const float*)d_in[15];
    const float* W2 = (const float*)d_in[16];
    const float* b2 = (const float*)d_in[17];
    const float* g1 = (const float*)d_in[18];
    const float* be1= (const float*)d_in[19];
    const float* g2 = (const float*)d_in[20];
    const float* be2= (const float*)d_in[21];
    const float* Wd1= (const float*)d_in[22];
    const float* bd1= (const float*)d_in[23];
    const float* Wd2= (const float*)d_in[24];
    const float* bd2= (const float*)d_in[25];
    const float* Wg = (const float*)d_in[26];
    const float* ag = (const float*)d_in[27];
    const float* Wgo= (const float*)d_in[28];
    const float* ago= (const float*)d_in[29];
    float* out = (float*)d_out;

    // workspace layout (~79.2 MB)
    float* ws = (float*)d_ws;
    float* h = ws;
    float* q = h + (size_t)MP * DM;
    unsigned short* hb   = (unsigned short*)(q + (size_t)MP * DM);
    unsigned short* qkvb = hb + (size_t)MP * DM;
    unsigned short* ob   = qkvb + (size_t)MP * QKVN;
    unsigned short* f1b  = qkvb;                    // alias qkvb+ob
    unsigned short* Wqkvt= ob + (size_t)MP * DM;
    unsigned short* Wot  = Wqkvt + (size_t)4 * QKVN * DM;
    unsigned short* W1t  = Wot + (size_t)4 * DM * DM;
    unsigned short* W2t  = W1t + (size_t)4 * DM * DFF;
    float* bqkv = (float*)(W2t + (size_t)4 * DFF * DM);
    float* dpart = bqkv + 4 * QKVN;
    unsigned short* vt = (unsigned short*)(dpart + NBATCH * 8 * MLPDIM);  // [40][64][TPAD]

    const long QS = (long)QKVN * DM;   // per-layer stride in Wqkvt
    wconv_kernel<<<dim3(DM/32,  DM/32,  4), 256, 0, stream>>>(Wq, Wqkvt,            DM,  DM, QS);
    wconv_kernel<<<dim3(DM/32,  DM/32,  4), 256, 0, stream>>>(Wk, Wqkvt + 512*512,  DM,  DM, QS);
    wconv_kernel<<<dim3(DM/32,  DM/32,  4), 256, 0, stream>>>(Wv, Wqkvt + 1024*512, DM,  DM, QS);
    wconv_kernel<<<dim3(DM/32,  DM/32,  4), 256, 0, stream>>>(Wo, Wot, DM,  DM, (long)DM*DM);
    wconv_kernel<<<dim3(DFF/32, DM/32,  4), 256, 0, stream>>>(W1, W1t, DM,  DFF, (long)DM*DFF);
    wconv_kernel<<<dim3(DM/32,  DFF/32, 4), 256, 0, stream>>>(W2, W2t, DFF, DM, (long)DFF*DM);
    bconcat_kernel<<<4, 512, 0, stream>>>(bq, bk, bv, bqkv);

    gat_kernel<<<NGRAPH, 64, 0, stream>>>(x, adj, Wg, ag, Wgo, ago, out + NBATCH * NCLS);
    encoder_kernel<<<ROWS, 256, 0, stream>>>(x, W_enc, b_enc, cls_tok, pos_emb, h, hb);

    dim3 g512 (DM  / 128, MP / 128);   // (4, 41)
    dim3 gqkv (QKVN / 128, MP / 128);  // (12, 41)
    dim3 g2048(DFF / 128, MP / 128);   // (16, 41)
    dim3 gAttn(TPAD / AQT, NBATCH * NHEAD);          // (17, 40)
    dim3 gVt  (TPAD / 64, NBATCH * NHEAD);           // (17, 40)
    int gLN = (ROWS + 3) / 4;

    for (int i = 0; i < 4; ++i) {
        gemm_mfma<<<gqkv, 256, 0, stream>>>(hb, Wqkvt + (size_t)i*QKVN*DM, bqkv + i*QKVN, nullptr, qkvb, QKVN, DM, 0);
        vtrans_kernel<<<gVt, 256, 0, stream>>>(qkvb + 1024, vt, QKVN);
        attn_mfma<<<gAttn, 256, 0, stream>>>(qkvb, qkvb + 512, vt, ob, QKVN);
        gemm_mfma<<<g512, 256, 0, stream>>>(ob, Wot + (size_t)i*DM*DM, bo + i*DM, q, nullptr, DM, DM, 0);
        add_ln_kernel<<<gLN, 256, 0, stream>>>(h, q, g1 + i*DM, be1 + i*DM, hb);
        gemm_mfma<<<g2048, 256, 0, stream>>>(hb,  W1t + (size_t)i*DM*DFF, b1 + i*DFF, nullptr, f1b, DFF, DM, 1);
        gemm_mfma<<<g512, 256, 0, stream>>>(f1b, W2t + (size_t)i*DM*DFF, b2 + i*DM,  q, nullptr, DM, DFF, 0);
        add_ln_kernel<<<gLN, 256, 0, stream>>>(h, q, g2 + i*DM, be2 + i*DM, hb);
    }

    dec1_kernel<<<dim3(8, NBATCH), 256, 0, stream>>>(h, Wd1, dpart);
    dec2_kernel<<<1, 256, 0, stream>>>(dpart, bd1, Wd2, bd2, out);
}

// Round 7
// 957.688 us; speedup vs baseline: 14.6291x; 1.0014x over previous
//
#include <hip/hip_runtime.h>
#include <hip/hip_bf16.h>
#include <math.h>

// ---------------------------------------------------------------------------
// Model constants
// ---------------------------------------------------------------------------
#define NBATCH 5
#define SEQ    1024
#define T      1025          // SEQ + 1 (cls token)
#define ROWS   (NBATCH * T)  // 5125
#define MP     5248          // ROWS padded to 41*128 for MFMA tiles
#define DM     512
#define DFF    2048
#define NHEAD  8
#define HD     64
#define NTOK   51
#define MLPDIM 256
#define NCLS   7
#define GH     3
#define GHID   64
#define GCLS   5
#define NGRAPH (SEQ * 5)     // 5120
#define QKVN   1536          // fused QKV output width
#define TPAD   1088          // T padded to 17*64 for V^T buffer

typedef __attribute__((ext_vector_type(8))) short bf16x8;
typedef __attribute__((ext_vector_type(4))) float f32x4;

#define GM_AS(p)  ((const __attribute__((address_space(1))) void*)(p))
#define LDS_AS(p) ((__attribute__((address_space(3))) void*)(p))

__device__ __forceinline__ unsigned short f2bf(float f) {
    unsigned int u = __float_as_uint(f);
    unsigned int r = (u + 0x7FFFu + ((u >> 16) & 1u)) >> 16;
    return (unsigned short)r;
}

// ---------------------------------------------------------------------------
// Weight transpose + fp32->bf16: W[K][N] (mat z at z*K*N) -> Wt (at z*dstride),
// layout [N][K]. dstride lets us interleave Wq/Wk/Wv per layer.
// ---------------------------------------------------------------------------
__global__ __launch_bounds__(256) void wconv_kernel(
    const float* __restrict__ W, unsigned short* __restrict__ Wt, int K, int N,
    long dstride)
{
    const float* Wm = W + (size_t)blockIdx.z * K * N;
    unsigned short* Wo = Wt + (size_t)blockIdx.z * dstride;
    __shared__ float tile[32][33];
    int bx = blockIdx.x * 32;   // N dir
    int by = blockIdx.y * 32;   // K dir
    int tx = threadIdx.x & 31, ty = threadIdx.x >> 5;   // 32 x 8
    #pragma unroll
    for (int i = 0; i < 32; i += 8)
        tile[ty + i][tx] = Wm[(size_t)(by + ty + i) * N + bx + tx];
    __syncthreads();
    #pragma unroll
    for (int i = 0; i < 32; i += 8)
        Wo[(size_t)(bx + ty + i) * K + by + tx] = f2bf(tile[tx][ty + i]);
}

// Concat per-layer biases bq|bk|bv -> bqkv[L][1536]
__global__ __launch_bounds__(512) void bconcat_kernel(
    const float* __restrict__ bq, const float* __restrict__ bk,
    const float* __restrict__ bv, float* __restrict__ bqkv)
{
    int i = blockIdx.x, t = threadIdx.x;
    bqkv[i * QKVN + t]        = bq[i * DM + t];
    bqkv[i * QKVN + 512 + t]  = bk[i * DM + t];
    bqkv[i * QKVN + 1024 + t] = bv[i * DM + t];
}

// ---------------------------------------------------------------------------
// bf16 MFMA GEMM: C[M][N] = A[M][K] @ Bt[N][K]^T + bias.
// 128x128 block tile, BK=64 (8 k-iters at K=512 -> fewer barrier drains),
// 256 threads = 4 waves in 2x2, each wave 64x64. global_load_lds width=16.
// ---------------------------------------------------------------------------
__global__ __launch_bounds__(256) void gemm_mfma(
    const unsigned short* __restrict__ A, const unsigned short* __restrict__ Bt,
    const float* __restrict__ bias, float* __restrict__ Cf,
    unsigned short* __restrict__ Cb, int N, int K, int relu)
{
    __shared__ unsigned short As[128 * 64];
    __shared__ unsigned short Bs[128 * 64];
    int tid = threadIdx.x;
    int l = tid & 63, w = tid >> 6;
    int wr = w & 1, wc = w >> 1;
    int mlane = l & 15, quad = l >> 4;
    int m0 = blockIdx.y * 128, n0 = blockIdx.x * 128;

    f32x4 acc[4][4] = {};   // [mi][ni]

    for (int k0 = 0; k0 < K; k0 += 64) {
        __syncthreads();
        #pragma unroll
        for (int it = 0; it < 4; ++it) {
            int c = tid + it * 256;          // 16B chunk id, 8 chunks/row
            int row = c >> 3, cc = c & 7;
            const unsigned short* ga = A  + (size_t)(m0 + row) * K + k0 + cc * 8;
            __builtin_amdgcn_global_load_lds(GM_AS(ga), LDS_AS(As + c * 8), 16, 0, 0);
            const unsigned short* gb = Bt + (size_t)(n0 + row) * K + k0 + cc * 8;
            __builtin_amdgcn_global_load_lds(GM_AS(gb), LDS_AS(Bs + c * 8), 16, 0, 0);
        }
        __syncthreads();
        #pragma unroll
        for (int half = 0; half < 2; ++half) {
            int ko = half * 32 + quad * 8;
            bf16x8 afrag[4], bfrag[4];
            #pragma unroll
            for (int mi = 0; mi < 4; ++mi)
                afrag[mi] = *(const bf16x8*)(As + (wr * 64 + mi * 16 + mlane) * 64 + ko);
            #pragma unroll
            for (int ni = 0; ni < 4; ++ni)
                bfrag[ni] = *(const bf16x8*)(Bs + (wc * 64 + ni * 16 + mlane) * 64 + ko);
            #pragma unroll
            for (int mi = 0; mi < 4; ++mi)
                #pragma unroll
                for (int ni = 0; ni < 4; ++ni)
                    acc[mi][ni] = __builtin_amdgcn_mfma_f32_16x16x32_bf16(
                        afrag[mi], bfrag[ni], acc[mi][ni], 0, 0, 0);
        }
    }

    // C/D layout: col = lane&15, row = quad*4 + reg
    #pragma unroll
    for (int mi = 0; mi < 4; ++mi) {
        #pragma unroll
        for (int r = 0; r < 4; ++r) {
            int gm = m0 + wr * 64 + mi * 16 + quad * 4 + r;
            size_t rowoff = (size_t)gm * N;
            #pragma unroll
            for (int ni = 0; ni < 4; ++ni) {
                int gn = n0 + wc * 64 + ni * 16 + mlane;
                float val = acc[mi][ni][r] + bias[gn];
                if (relu) val = fmaxf(val, 0.f);
                if (Cb) Cb[rowoff + gn] = f2bf(val);
                else    Cf[rowoff + gn] = val;
            }
        }
    }
}

// ---------------------------------------------------------------------------
// V transpose per layer: vb rows (b,t) stride qs, cols h*64+d  ->
// vt[(bh*64 + d)][TPAD] (key-major rows). One 64-key tile per block.
// ---------------------------------------------------------------------------
__global__ __launch_bounds__(256) void vtrans_kernel(
    const unsigned short* __restrict__ vb, unsigned short* __restrict__ vt, int qs)
{
    __shared__ unsigned short tile[64][72];
    int bh = blockIdx.y;
    int b = bh >> 3, h = bh & 7;
    int t0 = blockIdx.x * 64;
    int tid = threadIdx.x;
    #pragma unroll
    for (int it = 0; it < 2; ++it) {
        int c = tid + it * 256;
        int key = c >> 3, cc = c & 7;
        int gk = t0 + key; if (gk >= T) gk = T - 1;
        *(bf16x8*)(&tile[key][cc * 8]) =
            *(const bf16x8*)(vb + ((size_t)b * T + gk) * qs + h * HD + cc * 8);
    }
    __syncthreads();
    #pragma unroll
    for (int it = 0; it < 2; ++it) {
        int c = tid + it * 256;
        int d = c >> 3, cc = c & 7;
        unsigned short tmp[8];
        #pragma unroll
        for (int j = 0; j < 8; ++j) tmp[j] = tile[cc * 8 + j][d];
        *(bf16x8*)(vt + ((size_t)bh * 64 + d) * TPAD + t0 + cc * 8) = *(bf16x8*)tmp;
    }
}

// ---------------------------------------------------------------------------
// bf16 MFMA flash attention with register-prefetch pipeline.
// Block = 64 queries x (b,h); 4 waves, each 16 q. Chunk c+1's K/V global
// loads are issued into registers before computing chunk c, hiding the
// global latency behind MFMA+softmax work (waitcnt lands at the next
// reg->LDS write, after compute).
// ---------------------------------------------------------------------------
#define AQT 64
#define NCH 17   // ceil(T/64)
__global__ __launch_bounds__(256) void attn_mfma(
    const unsigned short* __restrict__ qb, const unsigned short* __restrict__ kb,
    const unsigned short* __restrict__ vt, unsigned short* __restrict__ ob,
    int qs)
{
    __shared__ unsigned short Ks[64 * 72];
    __shared__ unsigned short Vs[64 * 72];
    __shared__ unsigned short Ps[4][16 * 72];
    int bh = blockIdx.y;
    int b = bh >> 3, h = bh & 7;
    int t0 = blockIdx.x * AQT;
    int tid = threadIdx.x;
    int l = tid & 63, w = tid >> 6;
    int ml = l & 15, quad = l >> 4;
    size_t rowbase = (size_t)b * T;
    const unsigned short* vtb = vt + (size_t)bh * 64 * TPAD;

    int qrow = t0 + w * 16 + ml; if (qrow >= T) qrow = T - 1;
    const unsigned short* qp = qb + (rowbase + qrow) * qs + h * HD + quad * 8;
    bf16x8 qf0 = *(const bf16x8*)qp;
    bf16x8 qf1 = *(const bf16x8*)(qp + 32);

    // staging indices (fixed per thread)
    int c_a = tid, c_b = tid + 256;
    int rowa = c_a >> 3, cca = c_a & 7;   // rowa in 0..31
    int rowb = c_b >> 3, ccb = c_b & 7;   // rowb in 32..63

    f32x4 oacc[4] = {};
    float mrow[4] = {-1e30f, -1e30f, -1e30f, -1e30f};
    float lrow[4] = {0.f, 0.f, 0.f, 0.f};

    // prefetch chunk 0 into registers
    bf16x8 kra, krb, vra, vrb;
    {
        int gka = rowa; /* c0=0 */ int gkb = rowb;
        kra = *(const bf16x8*)(kb + (rowbase + gka) * qs + h * HD + cca * 8);
        krb = *(const bf16x8*)(kb + (rowbase + gkb) * qs + h * HD + ccb * 8);
        vra = *(const bf16x8*)(vtb + (size_t)rowa * TPAD + 0 + cca * 8);
        vrb = *(const bf16x8*)(vtb + (size_t)rowb * TPAD + 0 + ccb * 8);
    }

    for (int ch = 0; ch < NCH; ++ch) {
        int c0 = ch * 64;
        __syncthreads();
        *(bf16x8*)(Ks + rowa * 72 + cca * 8) = kra;
        *(bf16x8*)(Ks + rowb * 72 + ccb * 8) = krb;
        *(bf16x8*)(Vs + rowa * 72 + cca * 8) = vra;
        *(bf16x8*)(Vs + rowb * 72 + ccb * 8) = vrb;
        __syncthreads();
        if (ch + 1 < NCH) {
            int n0k = c0 + 64;
            int gka = n0k + rowa; if (gka >= T) gka = T - 1;
            int gkb = n0k + rowb; if (gkb >= T) gkb = T - 1;
            kra = *(const bf16x8*)(kb + (rowbase + gka) * qs + h * HD + cca * 8);
            krb = *(const bf16x8*)(kb + (rowbase + gkb) * qs + h * HD + ccb * 8);
            vra = *(const bf16x8*)(vtb + (size_t)rowa * TPAD + n0k + cca * 8);
            vrb = *(const bf16x8*)(vtb + (size_t)rowb * TPAD + n0k + ccb * 8);
        }

        // S = Q K^T
        f32x4 s[4] = {};
        #pragma unroll
        for (int ni = 0; ni < 4; ++ni) {
            bf16x8 kf0 = *(const bf16x8*)(Ks + (ni * 16 + ml) * 72 + quad * 8);
            bf16x8 kf1 = *(const bf16x8*)(Ks + (ni * 16 + ml) * 72 + 32 + quad * 8);
            s[ni] = __builtin_amdgcn_mfma_f32_16x16x32_bf16(qf0, kf0, s[ni], 0, 0, 0);
            s[ni] = __builtin_amdgcn_mfma_f32_16x16x32_bf16(qf1, kf1, s[ni], 0, 0, 0);
        }
        // scale + mask invalid keys
        #pragma unroll
        for (int ni = 0; ni < 4; ++ni) {
            bool valid = (c0 + ni * 16 + ml) < T;
            #pragma unroll
            for (int r = 0; r < 4; ++r)
                s[ni][r] = valid ? s[ni][r] * 0.125f : -1e30f;
        }
        // online softmax per row (row = quad*4+r; reduce over 16 ml lanes)
        #pragma unroll
        for (int r = 0; r < 4; ++r) {
            float mx = fmaxf(fmaxf(s[0][r], s[1][r]), fmaxf(s[2][r], s[3][r]));
            #pragma unroll
            for (int off = 1; off < 16; off <<= 1)
                mx = fmaxf(mx, __shfl_xor(mx, off));
            float mnew = fmaxf(mrow[r], mx);
            float alpha = __expf(mrow[r] - mnew);
            mrow[r] = mnew;
            float rs = 0.f;
            #pragma unroll
            for (int ni = 0; ni < 4; ++ni) {
                float p = __expf(s[ni][r] - mnew);
                s[ni][r] = p; rs += p;
            }
            #pragma unroll
            for (int off = 1; off < 16; off <<= 1)
                rs += __shfl_xor(rs, off);
            lrow[r] = lrow[r] * alpha + rs;
            #pragma unroll
            for (int ni = 0; ni < 4; ++ni) oacc[ni][r] *= alpha;
        }
        // P -> wave-private LDS with XOR swizzle
        unsigned short* pw = Ps[w];
        #pragma unroll
        for (int r = 0; r < 4; ++r)
            #pragma unroll
            for (int ni = 0; ni < 4; ++ni)
                pw[(quad * 4 + r) * 72 + ((ni * 16 + ml) ^ (quad << 4))] = f2bf(s[ni][r]);
        // O += P V (wave-private Ps; same-wave DS ordering, no barrier)
        int sw = ((ml >> 2) & 3) << 4;
        #pragma unroll
        for (int kc = 0; kc < 2; ++kc) {
            bf16x8 pf = *(const bf16x8*)(pw + ml * 72 + ((kc * 32 + quad * 8) ^ sw));
            #pragma unroll
            for (int ni = 0; ni < 4; ++ni) {
                bf16x8 vf = *(const bf16x8*)(Vs + (ni * 16 + ml) * 72 + kc * 32 + quad * 8);
                oacc[ni] = __builtin_amdgcn_mfma_f32_16x16x32_bf16(pf, vf, oacc[ni], 0, 0, 0);
            }
        }
    }

    // epilogue: O / l, write bf16
    #pragma unroll
    for (int r = 0; r < 4; ++r) {
        int grow = t0 + w * 16 + quad * 4 + r;
        if (grow >= T) continue;
        float inv = 1.f / lrow[r];
        unsigned short* op = ob + (rowbase + grow) * DM + h * HD;
        #pragma unroll
        for (int ni = 0; ni < 4; ++ni)
            op[ni * 16 + ml] = f2bf(oacc[ni][r] * inv);
    }
}

// ---------------------------------------------------------------------------
// Encoder: writes fp32 h and bf16 shadow hb
// ---------------------------------------------------------------------------
__global__ __launch_bounds__(256) void encoder_kernel(
    const float* __restrict__ x, const float* __restrict__ W_enc,
    const float* __restrict__ b_enc, const float* __restrict__ cls_tok,
    const float* __restrict__ pos_emb, float* __restrict__ h,
    unsigned short* __restrict__ hb)
{
    int row = blockIdx.x;
    int b = row / T, tt = row % T;
    int tid = threadIdx.x;
    float* hp = h + (size_t)row * DM;
    unsigned short* hbp = hb + (size_t)row * DM;
    if (tt == 0) {
        float a0 = cls_tok[tid]       + pos_emb[tid];
        float a1 = cls_tok[tid + 256] + pos_emb[tid + 256];
        hp[tid] = a0; hp[tid + 256] = a1;
        hbp[tid] = f2bf(a0); hbp[tid + 256] = f2bf(a1);
        return;
    }
    __shared__ float xs[NTOK];
    int s = tt - 1;
    if (tid < NTOK) xs[tid] = x[((size_t)b * SEQ + s) * NTOK + tid];
    __syncthreads();
    #pragma unroll
    for (int rep = 0; rep < 2; ++rep) {
        int d = tid + rep * 256;
        float acc = b_enc[d] + pos_emb[(size_t)tt * DM + d];
        for (int kx = 0; kx < NTOK; ++kx) acc += xs[kx] * W_enc[kx * DM + d];
        hp[d] = acc;
        hbp[d] = f2bf(acc);
    }
}

// ---------------------------------------------------------------------------
// Fused residual + LayerNorm, wave-per-row (4 rows / 256-thread block)
// ---------------------------------------------------------------------------
__global__ __launch_bounds__(256) void add_ln_kernel(
    float* __restrict__ h, const float* __restrict__ r,
    const float* __restrict__ g, const float* __restrict__ be,
    unsigned short* __restrict__ hb)
{
    int w = threadIdx.x >> 6, l = threadIdx.x & 63;
    int row = blockIdx.x * 4 + w;
    if (row >= ROWS) return;
    float* hp = h + (size_t)row * DM + l * 8;
    const float* rp = r + (size_t)row * DM + l * 8;
    unsigned short* hbp = hb + (size_t)row * DM + l * 8;
    float4 a0 = *(const float4*)(hp);
    float4 a1 = *(const float4*)(hp + 4);
    float4 b0 = *(const float4*)(rp);
    float4 b1 = *(const float4*)(rp + 4);
    float v[8] = {a0.x + b0.x, a0.y + b0.y, a0.z + b0.z, a0.w + b0.w,
                  a1.x + b1.x, a1.y + b1.y, a1.z + b1.z, a1.w + b1.w};
    float s = 0.f;
    #pragma unroll
    for (int i = 0; i < 8; ++i) s += v[i];
    #pragma unroll
    for (int off = 1; off < 64; off <<= 1) s += __shfl_xor(s, off);
    float mean = s * (1.f / DM);
    float sq = 0.f;
    #pragma unroll
    for (int i = 0; i < 8; ++i) { v[i] -= mean; sq += v[i] * v[i]; }
    #pragma unroll
    for (int off = 1; off < 64; off <<= 1) sq += __shfl_xor(sq, off);
    float inv = rsqrtf(sq * (1.f / DM) + 1e-5f);
    float4 g0 = *(const float4*)(g + l * 8);
    float4 g1 = *(const float4*)(g + l * 8 + 4);
    float4 e0 = *(const float4*)(be + l * 8);
    float4 e1 = *(const float4*)(be + l * 8 + 4);
    float o[8];
    o[0] = v[0]*inv*g0.x + e0.x; o[1] = v[1]*inv*g0.y + e0.y;
    o[2] = v[2]*inv*g0.z + e0.z; o[3] = v[3]*inv*g0.w + e0.w;
    o[4] = v[4]*inv*g1.x + e1.x; o[5] = v[5]*inv*g1.y + e1.y;
    o[6] = v[6]*inv*g1.z + e1.z; o[7] = v[7]*inv*g1.w + e1.w;
    *(float4*)(hp)     = make_float4(o[0], o[1], o[2], o[3]);
    *(float4*)(hp + 4) = make_float4(o[4], o[5], o[6], o[7]);
    ushort4 p0 = {f2bf(o[0]), f2bf(o[1]), f2bf(o[2]), f2bf(o[3])};
    ushort4 p1 = {f2bf(o[4]), f2bf(o[5]), f2bf(o[6]), f2bf(o[7])};
    *(ushort4*)(hbp)     = p0;
    *(ushort4*)(hbp + 4) = p1;
}

// ---------------------------------------------------------------------------
// Decoder stage 1 + stage 2
// ---------------------------------------------------------------------------
__global__ __launch_bounds__(256) void dec1_kernel(
    const float* __restrict__ h, const float* __restrict__ Wd1,
    float* __restrict__ part)
{
    int kc = blockIdx.x, b = blockIdx.y, tid = threadIdx.x;
    __shared__ float cs[64];
    const float* cls = h + (size_t)b * T * DM;
    if (tid < 64) cs[tid] = cls[kc * 64 + tid];
    __syncthreads();
    float acc = 0.f;
    #pragma unroll
    for (int kx = 0; kx < 64; ++kx)
        acc += cs[kx] * Wd1[(size_t)(kc * 64 + kx) * MLPDIM + tid];
    part[(size_t)(b * 8 + kc) * MLPDIM + tid] = acc;
}

__global__ __launch_bounds__(256) void dec2_kernel(
    const float* __restrict__ part, const float* __restrict__ bd1,
    const float* __restrict__ Wd2, const float* __restrict__ bd2,
    float* __restrict__ out)
{
    __shared__ float t1s[MLPDIM];
    int tid = threadIdx.x;
    for (int b = 0; b < NBATCH; ++b) {
        float acc = bd1[tid];
        #pragma unroll
        for (int kc = 0; kc < 8; ++kc)
            acc += part[(size_t)(b * 8 + kc) * MLPDIM + tid];
        t1s[tid] = acc;
        __syncthreads();
        if (tid < NCLS) {
            float a2 = bd2[tid];
            for (int kx = 0; kx < MLPDIM; ++kx) a2 += t1s[kx] * Wd2[kx * NCLS + tid];
            out[b * NCLS + tid] = a2;
        }
        __syncthreads();
    }
}

// ---------------------------------------------------------------------------
// GAT (unchanged)
// ---------------------------------------------------------------------------
__global__ __launch_bounds__(64) void gat_kernel(
    const float* __restrict__ x, const int* __restrict__ adj,
    const float* __restrict__ Wg, const float* __restrict__ ag,
    const float* __restrict__ Wgo, const float* __restrict__ ago,
    float* __restrict__ out)
{
    int g = blockIdx.x;
    int s = g / 5, jj = g % 5;
    int tid = threadIdx.x;
    __shared__ float xs[5][3];
    __shared__ int adjs[25];
    __shared__ float hb[GH][5][GHID];
    __shared__ float o1[GH][5][GHID];
    __shared__ float srcb[GH][5], dstb[GH][5];
    __shared__ float attb[GH][5][5];
    __shared__ float h2[5][5], src2[5], dst2[5], att2[5][5], o2[5][5];

    if (tid < 15) { int n = tid / 3, c = tid % 3;
        xs[n][c] = x[(size_t)n * SEQ * NTOK + (size_t)s * NTOK + jj * 3 + c]; }
    if (tid < 25) adjs[tid] = adj[tid];
    __syncthreads();

    #pragma unroll
    for (int hh = 0; hh < GH; ++hh)
        #pragma unroll
        for (int n = 0; n < 5; ++n)
            hb[hh][n][tid] = xs[n][0] * Wg[hh * 192 + tid]
                           + xs[n][1] * Wg[hh * 192 + 64 + tid]
                           + xs[n][2] * Wg[hh * 192 + 128 + tid];
    __syncthreads();

    if (tid < 15) { int hh = tid / 5, n = tid % 5; float a = 0.f;
        for (int f = 0; f < GHID; ++f) a += hb[hh][n][f] * ag[hh * 128 + f];
        srcb[hh][n] = a;
    } else if (tid >= 32 && tid < 47) { int t2 = tid - 32; int hh = t2 / 5, n = t2 % 5; float a = 0.f;
        for (int f = 0; f < GHID; ++f) a += hb[hh][n][f] * ag[hh * 128 + 64 + f];
        dstb[hh][n] = a;
    }
    __syncthreads();

    if (tid < 15) { int hh = tid / 5, i = tid % 5;
        float e[5]; float mx = -1e30f;
        #pragma unroll
        for (int j2 = 0; j2 < 5; ++j2) {
            float ev = srcb[hh][i] + dstb[hh][j2];
            ev = ev > 0.f ? ev : 0.2f * ev;
            e[j2] = ev;
            if (adjs[i * 5 + j2] && ev > mx) mx = ev;
        }
        float sum = 0.f;
        #pragma unroll
        for (int j2 = 0; j2 < 5; ++j2) {
            float p = adjs[i * 5 + j2] ? expf(e[j2] - mx) : 0.f;
            e[j2] = p; sum += p;
        }
        float inv = 1.f / sum;
        #pragma unroll
        for (int j2 = 0; j2 < 5; ++j2) attb[hh][i][j2] = e[j2] * inv;
    }
    __syncthreads();

    #pragma unroll
    for (int hh = 0; hh < GH; ++hh)
        #pragma unroll
        for (int n = 0; n < 5; ++n) {
            float a = 0.f;
            #pragma unroll
            for (int j2 = 0; j2 < 5; ++j2) a += attb[hh][n][j2] * hb[hh][j2][tid];
            o1[hh][n][tid] = a > 0.f ? a : expm1f(a);
        }
    __syncthreads();

    if (tid < 25) { int n = tid / 5, m = tid % 5; float a = 0.f;
        for (int hh = 0; hh < GH; ++hh)
            for (int f = 0; f < GHID; ++f)
                a += o1[hh][n][f] * Wgo[(hh * GHID + f) * GCLS + m];
        h2[n][m] = a;
    }
    __syncthreads();

    if (tid < 5) { float a = 0.f;
        for (int m = 0; m < GCLS; ++m) a += h2[tid][m] * ago[m];
        src2[tid] = a;
    } else if (tid >= 8 && tid < 13) { int n = tid - 8; float a = 0.f;
        for (int m = 0; m < GCLS; ++m) a += h2[n][m] * ago[GCLS + m];
        dst2[n] = a;
    }
    __syncthreads();

    if (tid < 5) { int i = tid;
        float e[5]; float mx = -1e30f;
        #pragma unroll
        for (int j2 = 0; j2 < 5; ++j2) {
            float ev = src2[i] + dst2[j2];
            ev = ev > 0.f ? ev : 0.2f * ev;
            e[j2] = ev;
            if (adjs[i * 5 + j2] && ev > mx) mx = ev;
        }
        float sum = 0.f;
        #pragma unroll
        for (int j2 = 0; j2 < 5; ++j2) {
            float p = adjs[i * 5 + j2] ? expf(e[j2] - mx) : 0.f;
            e[j2] = p; sum += p;
        }
        float inv = 1.f / sum;
        #pragma unroll
        for (int j2 = 0; j2 < 5; ++j2) att2[i][j2] = e[j2] * inv;
    }
    __syncthreads();

    if (tid < 25) { int n = tid / 5, m = tid % 5; float a = 0.f;
        #pragma unroll
        for (int j2 = 0; j2 < 5; ++j2) a += att2[n][j2] * h2[j2][m];
        o2[n][m] = a > 0.f ? a : expm1f(a);
    }
    __syncthreads();

    if (tid < 5) { int n = tid;
        float mx = o2[n][0];
        #pragma unroll
        for (int m = 1; m < GCLS; ++m) mx = fmaxf(mx, o2[n][m]);
        float sum = 0.f;
        #pragma unroll
        for (int m = 0; m < GCLS; ++m) sum += expf(o2[n][m] - mx);
        float ls = logf(sum);
        #pragma unroll
        for (int m = 0; m < GCLS; ++m)
            out[(size_t)g * 25 + n * 5 + m] = o2[n][m] - mx - ls;
    }
}

// ---------------------------------------------------------------------------
// Launch
// ---------------------------------------------------------------------------
extern "C" void kernel_launch(void* const* d_in, const int* in_sizes, int n_in,
                              void* d_out, int out_size, void* d_ws, size_t ws_size,
                              hipStream_t stream)
{
    const float* x       = (const float*)d_in[0];
    const int*   adj     = (const int*)  d_in[1];
    const float* W_enc   = (const float*)d_in[2];
    const float* b_enc   = (const float*)d_in[3];
    const float* cls_tok = (const float*)d_in[4];
    const float* pos_emb = (const float*)d_in[5];
    const float* Wq = (const float*)d_in[6];
    const float* bq = (const float*)d_in[7];
    const float* Wk = (const float*)d_in[8];
    const float* bk = (const float*)d_in[9];
    const float* Wv = (const float*)d_in[10];
    const float* bv = (const float*)d_in[11];
    const float* Wo = (const float*)d_in[12];
    const float* bo = (const float*)d_in[13];
    const float* W1 = (const float*)d_in[14];
    const float* b1 = (const float*)d_in[15];
    const float* W2 = (const float*)d_in[16];
    const float* b2 = (const float*)d_in[17];
    const float* g1 = (const float*)d_in[18];
    const float* be1= (const float*)d_in[19];
    const float* g2 = (const float*)d_in[20];
    const float* be2= (const float*)d_in[21];
    const float* Wd1= (const float*)d_in[22];
    const float* bd1= (const float*)d_in[23];
    const float* Wd2= (const float*)d_in[24];
    const float* bd2= (const float*)d_in[25];
    const float* Wg = (const float*)d_in[26];
    const float* ag = (const float*)d_in[27];
    const float* Wgo= (const float*)d_in[28];
    const float* ago= (const float*)d_in[29];
    float* out = (float*)d_out;

    // workspace layout (~79.2 MB)
    float* ws = (float*)d_ws;
    float* h = ws;
    float* q = h + (size_t)MP * DM;
    unsigned short* hb   = (unsigned short*)(q + (size_t)MP * DM);
    unsigned short* qkvb = hb + (size_t)MP * DM;
    unsigned short* ob   = qkvb + (size_t)MP * QKVN;
    unsigned short* f1b  = qkvb;                    // alias qkvb+ob
    unsigned short* Wqkvt= ob + (size_t)MP * DM;
    unsigned short* Wot  = Wqkvt + (size_t)4 * QKVN * DM;
    unsigned short* W1t  = Wot + (size_t)4 * DM * DM;
    unsigned short* W2t  = W1t + (size_t)4 * DM * DFF;
    float* bqkv = (float*)(W2t + (size_t)4 * DFF * DM);
    float* dpart = bqkv + 4 * QKVN;
    unsigned short* vt = (unsigned short*)(dpart + NBATCH * 8 * MLPDIM);  // [40][64][TPAD]

    const long QS = (long)QKVN * DM;   // per-layer stride in Wqkvt
    wconv_kernel<<<dim3(DM/32,  DM/32,  4), 256, 0, stream>>>(Wq, Wqkvt,            DM,  DM, QS);
    wconv_kernel<<<dim3(DM/32,  DM/32,  4), 256, 0, stream>>>(Wk, Wqkvt + 512*512,  DM,  DM, QS);
    wconv_kernel<<<dim3(DM/32,  DM/32,  4), 256, 0, stream>>>(Wv, Wqkvt + 1024*512, DM,  DM, QS);
    wconv_kernel<<<dim3(DM/32,  DM/32,  4), 256, 0, stream>>>(Wo, Wot, DM,  DM, (long)DM*DM);
    wconv_kernel<<<dim3(DFF/32, DM/32,  4), 256, 0, stream>>>(W1, W1t, DM,  DFF, (long)DM*DFF);
    wconv_kernel<<<dim3(DM/32,  DFF/32, 4), 256, 0, stream>>>(W2, W2t, DFF, DM, (long)DFF*DM);
    bconcat_kernel<<<4, 512, 0, stream>>>(bq, bk, bv, bqkv);

    gat_kernel<<<NGRAPH, 64, 0, stream>>>(x, adj, Wg, ag, Wgo, ago, out + NBATCH * NCLS);
    encoder_kernel<<<ROWS, 256, 0, stream>>>(x, W_enc, b_enc, cls_tok, pos_emb, h, hb);

    dim3 g512 (DM  / 128, MP / 128);   // (4, 41)
    dim3 gqkv (QKVN / 128, MP / 128);  // (12, 41)
    dim3 g2048(DFF / 128, MP / 128);   // (16, 41)
    dim3 gAttn(TPAD / AQT, NBATCH * NHEAD);          // (17, 40)
    dim3 gVt  (TPAD / 64, NBATCH * NHEAD);           // (17, 40)
    int gLN = (ROWS + 3) / 4;

    for (int i = 0; i < 4; ++i) {
        gemm_mfma<<<gqkv, 256, 0, stream>>>(hb, Wqkvt + (size_t)i*QKVN*DM, bqkv + i*QKVN, nullptr, qkvb, QKVN, DM, 0);
        vtrans_kernel<<<gVt, 256, 0, stream>>>(qkvb + 1024, vt, QKVN);
        attn_mfma<<<gAttn, 256, 0, stream>>>(qkvb, qkvb + 512, vt, ob, QKVN);
        gemm_mfma<<<g512, 256, 0, stream>>>(ob, Wot + (size_t)i*DM*DM, bo + i*DM, q, nullptr, DM, DM, 0);
        add_ln_kernel<<<gLN, 256, 0, stream>>>(h, q, g1 + i*DM, be1 + i*DM, hb);
        gemm_mfma<<<g2048, 256, 0, stream>>>(hb,  W1t + (size_t)i*DM*DFF, b1 + i*DFF, nullptr, f1b, DFF, DM, 1);
        gemm_mfma<<<g512, 256, 0, stream>>>(f1b, W2t + (size_t)i*DM*DFF, b2 + i*DM,  q, nullptr, DM, DFF, 0);
        add_ln_kernel<<<gLN, 256, 0, stream>>>(h, q, g2 + i*DM, be2 + i*DM, hb);
    }

    dec1_kernel<<<dim3(8, NBATCH), 256, 0, stream>>>(h, Wd1, dpart);
    dec2_kernel<<<1, 256, 0, stream>>>(dpart, bd1, Wd2, bd2, out);
}